// Round 2
// baseline (3715.771 us; speedup 1.0000x reference)
//
#include <hip/hip_runtime.h>
#include <cmath>

#define Ss 4096
#define NCh 16
#define CK 256

typedef unsigned short bfu;

__device__ __forceinline__ float bf2f(unsigned short u) {
    union { unsigned u32; float f; } v; v.u32 = ((unsigned)u) << 16; return v.f;
}
__device__ __forceinline__ unsigned short f2bf(float f) {
    union { float f; unsigned u; } v; v.f = f;
    unsigned r = v.u + 0x7fff + ((v.u >> 16) & 1);
    return (unsigned short)(r >> 16);
}

// ---------------------------------------------------------------------------
// RoPE cos/sin table: [s][d], d<64 -> freq d, d>=64 -> freq d-64
// ---------------------------------------------------------------------------
__global__ void rope_table(float* __restrict__ cosT, float* __restrict__ sinT) {
    int id = blockIdx.x * 256 + threadIdx.x;      // 4096*128
    int d = id & 127, s = id >> 7;
    int f = d & 63;
    float e = (2.0f * (float)f) / 128.0f;
    float inv = 1.0f / powf(10000.0f, e);
    float ang = (float)s * inv;
    cosT[id] = cosf(ang);
    sinT[id] = sinf(ang);
}

// ---------------------------------------------------------------------------
// QKV GEMM (fp32 x fp32) + fused RoPE + elu+1 + bf16 store to q/k/v buffers.
// C-tile = x[8192,2048] @ Wqkv[6144,2048]^T. Grid (48,64), 256 thr.
// ---------------------------------------------------------------------------
__global__ __launch_bounds__(256) void qkv_rope_gemm(
    const float* __restrict__ A, const float* __restrict__ B,
    const float* __restrict__ cosT, const float* __restrict__ sinT,
    bfu* __restrict__ qb, bfu* __restrict__ kbuf, bfu* __restrict__ vbuf)
{
    __shared__ float As[8][128];
    __shared__ float Bs[8][128];
    const int tid = threadIdx.x;
    const int bm = blockIdx.y * 128;
    const int bn = blockIdx.x * 128;
    const int lrow = tid >> 1;
    const int lk   = (tid & 1) * 4;
    const int ty = tid >> 4, tx = tid & 15;
    float acc[8][8] = {};
    const float* Arow = A + (size_t)(bm + lrow) * 2048 + lk;
    const float* Brow = B + (size_t)(bn + lrow) * 2048 + lk;
    for (int k0 = 0; k0 < 2048; k0 += 8) {
        float4 a4 = *(const float4*)(Arow + k0);
        float4 b4 = *(const float4*)(Brow + k0);
        __syncthreads();
        As[lk+0][lrow]=a4.x; As[lk+1][lrow]=a4.y; As[lk+2][lrow]=a4.z; As[lk+3][lrow]=a4.w;
        Bs[lk+0][lrow]=b4.x; Bs[lk+1][lrow]=b4.y; Bs[lk+2][lrow]=b4.z; Bs[lk+3][lrow]=b4.w;
        __syncthreads();
#pragma unroll
        for (int kk = 0; kk < 8; ++kk) {
            float4 a0 = *(const float4*)&As[kk][ty*8];
            float4 a1 = *(const float4*)&As[kk][ty*8+4];
            float4 b0 = *(const float4*)&Bs[kk][tx*8];
            float4 b1 = *(const float4*)&Bs[kk][tx*8+4];
            float av[8] = {a0.x,a0.y,a0.z,a0.w,a1.x,a1.y,a1.z,a1.w};
            float bv[8] = {b0.x,b0.y,b0.z,b0.w,b1.x,b1.y,b1.z,b1.w};
#pragma unroll
            for (int i=0;i<8;i++)
#pragma unroll
                for (int j=0;j<8;j++) acc[i][j] += av[i]*bv[j];
        }
    }
    const int part = bn >> 11;            // 0=q 1=k 2=v
    const int colh = bn & 2047;           // col within part (head-aligned, 128-mult)
    bfu* outp = (part == 0) ? qb : (part == 1) ? kbuf : vbuf;
#pragma unroll
    for (int i=0;i<8;i++) {
        int row = bm + ty*8 + i;
        int s = row & 4095;
        float vals[8];
#pragma unroll
        for (int j=0;j<8;j++) vals[j] = acc[i][j];
        if (part < 2) {
#pragma unroll
            for (int jp=0;jp<4;jp++) {
                int d0 = tx*8 + jp*2;     // within-head dim (bn 128-aligned)
                float c0 = cosT[s*128 + d0],   c1 = cosT[s*128 + d0 + 1];
                float s0 = sinT[s*128 + d0],   s1 = sinT[s*128 + d0 + 1];
                float a = vals[2*jp], b2 = vals[2*jp+1];
                float n0 = a*c0 - b2*s0;
                float n1 = b2*c1 + a*s1;
                vals[2*jp]   = n0 > 0.0f ? n0 + 1.0f : __expf(n0);
                vals[2*jp+1] = n1 > 0.0f ? n1 + 1.0f : __expf(n1);
            }
        }
        bfu t[8];
#pragma unroll
        for (int j=0;j<8;j++) t[j] = f2bf(vals[j]);
        *(uint4*)(outp + (size_t)row * 2048 + colh + tx*8) = *(uint4*)t;
    }
}

// ---------------------------------------------------------------------------
// Per (b,h,c): Sc[d][e] = sum_l k[l][d]*v[l][e]; Zc[d] = sum_l k[l][d]
// 512 blocks, K=256 (chunk len). bf16 in, fp32 out.
// ---------------------------------------------------------------------------
__global__ __launch_bounds__(256) void kv_outer(const bfu* __restrict__ kbuf,
                                                const bfu* __restrict__ vbuf,
                                                float* __restrict__ Sc, float* __restrict__ Zc)
{
    int batch = blockIdx.x;
    int c = batch & 15, h = (batch >> 4) & 15, b = batch >> 8;
    const int row0 = b*Ss + c*CK;
    const bfu* Kp = kbuf + (size_t)row0 * 2048 + h*128;
    const bfu* Vp = vbuf + (size_t)row0 * 2048 + h*128;
    __shared__ float Ks[8][128];
    __shared__ float Vs[8][128];
    const int tid = threadIdx.x;
    const int row = tid >> 5;
    const int col = (tid & 31) * 4;
    const int ty = tid >> 4, tx = tid & 15;
    float acc[8][8] = {};
    float zacc[8] = {};
    for (int l0 = 0; l0 < CK; l0 += 8) {
        ushort4 k4 = *(const ushort4*)(Kp + (size_t)(l0 + row) * 2048 + col);
        ushort4 v4 = *(const ushort4*)(Vp + (size_t)(l0 + row) * 2048 + col);
        __syncthreads();
        Ks[row][col+0]=bf2f(k4.x); Ks[row][col+1]=bf2f(k4.y); Ks[row][col+2]=bf2f(k4.z); Ks[row][col+3]=bf2f(k4.w);
        Vs[row][col+0]=bf2f(v4.x); Vs[row][col+1]=bf2f(v4.y); Vs[row][col+2]=bf2f(v4.z); Vs[row][col+3]=bf2f(v4.w);
        __syncthreads();
#pragma unroll
        for (int kk = 0; kk < 8; ++kk) {
            float4 a0 = *(const float4*)&Ks[kk][ty*8];
            float4 a1 = *(const float4*)&Ks[kk][ty*8+4];
            float4 b0 = *(const float4*)&Vs[kk][tx*8];
            float4 b1 = *(const float4*)&Vs[kk][tx*8+4];
            float av[8] = {a0.x,a0.y,a0.z,a0.w,a1.x,a1.y,a1.z,a1.w};
            float bv[8] = {b0.x,b0.y,b0.z,b0.w,b1.x,b1.y,b1.z,b1.w};
#pragma unroll
            for (int i=0;i<8;i++) {
#pragma unroll
                for (int j=0;j<8;j++) acc[i][j] += av[i]*bv[j];
                if (tx == 0) zacc[i] += av[i];
            }
        }
    }
    float* Sout = Sc + (size_t)batch * 16384;
#pragma unroll
    for (int i=0;i<8;i++) {
        float* crow = Sout + (size_t)(ty*8+i)*128 + tx*8;
        *(float4*)crow     = make_float4(acc[i][0],acc[i][1],acc[i][2],acc[i][3]);
        *(float4*)(crow+4) = make_float4(acc[i][4],acc[i][5],acc[i][6],acc[i][7]);
    }
    if (tx == 0) {
#pragma unroll
        for (int i=0;i<8;i++) Zc[(size_t)batch*128 + ty*8 + i] = zacc[i];
    }
}

// ---------------------------------------------------------------------------
// Exclusive prefix over chunks (16), in place.
// ---------------------------------------------------------------------------
__global__ void prefix_S(float* __restrict__ Sc) {
    size_t idx = (size_t)blockIdx.x * 256 + threadIdx.x;  // 32*16384
    size_t bh = idx >> 14;
    size_t de = idx & 16383;
    float* p = Sc + bh * (size_t)NCh * 16384 + de;
    float run = 0.0f;
#pragma unroll
    for (int c = 0; c < NCh; ++c) {
        float t = p[(size_t)c * 16384];
        p[(size_t)c * 16384] = run;
        run += t;
    }
}
__global__ void prefix_Z(float* __restrict__ Zc) {
    size_t idx = (size_t)blockIdx.x * 256 + threadIdx.x;  // 32*128
    size_t bh = idx >> 7;
    size_t d = idx & 127;
    float* p = Zc + bh * (size_t)NCh * 128 + d;
    float run = 0.0f;
#pragma unroll
    for (int c = 0; c < NCh; ++c) {
        float t = p[(size_t)c * 128];
        p[(size_t)c * 128] = run;
        run += t;
    }
}

// ---------------------------------------------------------------------------
// Fused chunk attention: per (half, batch) block of 128 q-rows:
//   for kb<=half: att_tile = mask(q@k^T) -> LDS (K-major attkm[m][l])
//                 num += att_tile@v ; den += rowsum(att_tile)
//   then num += q@S_state ; den += q.Z ; ao = num/max(den,1e-6) (bf16)
// Grid (2, 512), 256 thr. LDS ~76 KB.
// ---------------------------------------------------------------------------
__global__ __launch_bounds__(256) void chunk_fused(
    const bfu* __restrict__ qb, const bfu* __restrict__ kbuf, const bfu* __restrict__ vbuf,
    const float* __restrict__ Sc, const float* __restrict__ Zc, bfu* __restrict__ ao)
{
    __shared__ float attkm[128][132];
    __shared__ float As[8][128];
    __shared__ float Bs[8][128];
    __shared__ float Zs[128];
    const int half = blockIdx.x, batch = blockIdx.y;
    const int c = batch & 15, h = (batch >> 4) & 15, b = batch >> 8;
    const int row0 = b*Ss + c*CK;
    const int tid = threadIdx.x;
    const int lrow = tid >> 1;
    const int lk   = (tid & 1) * 4;
    const int brow = tid >> 5;
    const int bcol = (tid & 31) * 4;
    const int ty = tid >> 4, tx = tid & 15;
    float num[8][8] = {};
    float den[8] = {};
    if (tid < 128) Zs[tid] = Zc[(size_t)batch * 128 + tid];
    const bfu* qbase = qb + (size_t)(row0 + half*128) * 2048 + h*128;

    for (int kb_ = 0; kb_ <= half; ++kb_) {
        float acc[8][8] = {};
        const bfu* kbase = kbuf + (size_t)(row0 + kb_*128) * 2048 + h*128;
        for (int k0 = 0; k0 < 128; k0 += 8) {
            ushort4 qa = *(const ushort4*)(qbase + (size_t)lrow * 2048 + k0 + lk);
            ushort4 ka = *(const ushort4*)(kbase + (size_t)lrow * 2048 + k0 + lk);
            __syncthreads();
            As[lk+0][lrow]=bf2f(qa.x); As[lk+1][lrow]=bf2f(qa.y); As[lk+2][lrow]=bf2f(qa.z); As[lk+3][lrow]=bf2f(qa.w);
            Bs[lk+0][lrow]=bf2f(ka.x); Bs[lk+1][lrow]=bf2f(ka.y); Bs[lk+2][lrow]=bf2f(ka.z); Bs[lk+3][lrow]=bf2f(ka.w);
            __syncthreads();
#pragma unroll
            for (int kk = 0; kk < 8; ++kk) {
                float4 a0 = *(const float4*)&As[kk][ty*8];
                float4 a1 = *(const float4*)&As[kk][ty*8+4];
                float4 b0 = *(const float4*)&Bs[kk][tx*8];
                float4 b1 = *(const float4*)&Bs[kk][tx*8+4];
                float av[8] = {a0.x,a0.y,a0.z,a0.w,a1.x,a1.y,a1.z,a1.w};
                float bv[8] = {b0.x,b0.y,b0.z,b0.w,b1.x,b1.y,b1.z,b1.w};
#pragma unroll
                for (int i=0;i<8;i++)
#pragma unroll
                    for (int j=0;j<8;j++) acc[i][j] += av[i]*bv[j];
            }
        }
        // mask + write K-major att tile: attkm[m][l]
        const bool needmask = (kb_ == half);
#pragma unroll
        for (int j=0;j<8;j++) {
            int m = tx*8 + j;
            int mg = kb_*128 + m;
            float o[8];
#pragma unroll
            for (int i=0;i<8;i++) {
                int lg = half*128 + ty*8 + i;
                o[i] = (!needmask || lg >= mg) ? acc[i][j] : 0.0f;
            }
            *(float4*)&attkm[m][ty*8]   = make_float4(o[0],o[1],o[2],o[3]);
            *(float4*)&attkm[m][ty*8+4] = make_float4(o[4],o[5],o[6],o[7]);
        }
        // num += att_tile @ v ; den += rowsum(att_tile)
        const bfu* vbase = vbuf + (size_t)(row0 + kb_*128) * 2048 + h*128;
        for (int k0 = 0; k0 < 128; k0 += 8) {
            ushort4 va = *(const ushort4*)(vbase + (size_t)(k0 + brow) * 2048 + bcol);
            __syncthreads();   // also orders attkm writes above vs reads below
            Bs[brow][bcol+0]=bf2f(va.x); Bs[brow][bcol+1]=bf2f(va.y); Bs[brow][bcol+2]=bf2f(va.z); Bs[brow][bcol+3]=bf2f(va.w);
            __syncthreads();
#pragma unroll
            for (int kk = 0; kk < 8; ++kk) {
                float4 a0 = *(const float4*)&attkm[k0+kk][ty*8];
                float4 a1 = *(const float4*)&attkm[k0+kk][ty*8+4];
                float4 b0 = *(const float4*)&Bs[kk][tx*8];
                float4 b1 = *(const float4*)&Bs[kk][tx*8+4];
                float av[8] = {a0.x,a0.y,a0.z,a0.w,a1.x,a1.y,a1.z,a1.w};
                float bv[8] = {b0.x,b0.y,b0.z,b0.w,b1.x,b1.y,b1.z,b1.w};
#pragma unroll
                for (int i=0;i<8;i++) {
                    den[i] += av[i];
#pragma unroll
                    for (int j=0;j<8;j++) num[i][j] += av[i]*bv[j];
                }
            }
        }
    }
    // num += q @ S_state ; den += q . Z
    const float* Sbase = Sc + (size_t)batch * 16384;
    for (int k0 = 0; k0 < 128; k0 += 8) {
        ushort4 qa = *(const ushort4*)(qbase + (size_t)lrow * 2048 + k0 + lk);
        float4 sb = *(const float4*)(Sbase + (size_t)(k0 + brow) * 128 + bcol);
        __syncthreads();
        As[lk+0][lrow]=bf2f(qa.x); As[lk+1][lrow]=bf2f(qa.y); As[lk+2][lrow]=bf2f(qa.z); As[lk+3][lrow]=bf2f(qa.w);
        *(float4*)&Bs[brow][bcol] = sb;
        __syncthreads();
#pragma unroll
        for (int kk = 0; kk < 8; ++kk) {
            float4 a0 = *(const float4*)&As[kk][ty*8];
            float4 a1 = *(const float4*)&As[kk][ty*8+4];
            float4 b0 = *(const float4*)&Bs[kk][tx*8];
            float4 b1 = *(const float4*)&Bs[kk][tx*8+4];
            float av[8] = {a0.x,a0.y,a0.z,a0.w,a1.x,a1.y,a1.z,a1.w};
            float bv[8] = {b0.x,b0.y,b0.z,b0.w,b1.x,b1.y,b1.z,b1.w};
            float zv = Zs[k0+kk];
#pragma unroll
            for (int i=0;i<8;i++) {
                den[i] += av[i]*zv;
#pragma unroll
                for (int j=0;j<8;j++) num[i][j] += av[i]*bv[j];
            }
        }
    }
    bfu* aop = ao + (size_t)(row0 + half*128) * 2048 + h*128;
#pragma unroll
    for (int i=0;i<8;i++) {
        float dv = den[i] > 1e-6f ? den[i] : 1e-6f;
        float inv = 1.0f / dv;
        bfu t[8];
#pragma unroll
        for (int j=0;j<8;j++) t[j] = f2bf(num[i][j]*inv);
        *(uint4*)(aop + (size_t)(ty*8+i)*2048 + tx*8) = *(uint4*)t;
    }
}

// ---------------------------------------------------------------------------
// Final GEMM: out[8192,2048] = ao(bf16)[8192,2048] @ Wout(fp32)[2048,2048]^T
// ---------------------------------------------------------------------------
__global__ __launch_bounds__(256) void sgemm_abf(
    const bfu* __restrict__ A, const float* __restrict__ B, float* __restrict__ C)
{
    __shared__ float As[8][128];
    __shared__ float Bs[8][128];
    const int tid = threadIdx.x;
    const int bm = blockIdx.y * 128;
    const int bn = blockIdx.x * 128;
    const int lrow = tid >> 1;
    const int lk   = (tid & 1) * 4;
    const int ty = tid >> 4, tx = tid & 15;
    float acc[8][8] = {};
    const bfu*   Arow = A + (size_t)(bm + lrow) * 2048 + lk;
    const float* Brow = B + (size_t)(bn + lrow) * 2048 + lk;
    for (int k0 = 0; k0 < 2048; k0 += 8) {
        ushort4 a4 = *(const ushort4*)(Arow + k0);
        float4  b4 = *(const float4*)(Brow + k0);
        __syncthreads();
        As[lk+0][lrow]=bf2f(a4.x); As[lk+1][lrow]=bf2f(a4.y); As[lk+2][lrow]=bf2f(a4.z); As[lk+3][lrow]=bf2f(a4.w);
        Bs[lk+0][lrow]=b4.x; Bs[lk+1][lrow]=b4.y; Bs[lk+2][lrow]=b4.z; Bs[lk+3][lrow]=b4.w;
        __syncthreads();
#pragma unroll
        for (int kk = 0; kk < 8; ++kk) {
            float4 a0 = *(const float4*)&As[kk][ty*8];
            float4 a1 = *(const float4*)&As[kk][ty*8+4];
            float4 b0 = *(const float4*)&Bs[kk][tx*8];
            float4 b1 = *(const float4*)&Bs[kk][tx*8+4];
            float av[8] = {a0.x,a0.y,a0.z,a0.w,a1.x,a1.y,a1.z,a1.w};
            float bv[8] = {b0.x,b0.y,b0.z,b0.w,b1.x,b1.y,b1.z,b1.w};
#pragma unroll
            for (int i=0;i<8;i++)
#pragma unroll
                for (int j=0;j<8;j++) acc[i][j] += av[i]*bv[j];
        }
    }
#pragma unroll
    for (int i=0;i<8;i++) {
        float* crow = C + (size_t)(bm + ty*8 + i) * 2048 + bn + tx*8;
        *(float4*)crow     = make_float4(acc[i][0],acc[i][1],acc[i][2],acc[i][3]);
        *(float4*)(crow+4) = make_float4(acc[i][4],acc[i][5],acc[i][6],acc[i][7]);
    }
}

// ---------------------------------------------------------------------------
extern "C" void kernel_launch(void* const* d_in, const int* in_sizes, int n_in,
                              void* d_out, int out_size, void* d_ws, size_t ws_size,
                              hipStream_t stream)
{
    const float* x    = (const float*)d_in[0];
    const float* Wqkv = (const float*)d_in[1];
    const float* Wout = (const float*)d_in[2];
    float* out = (float*)d_out;

    // workspace: ~165 MB total
    float* cosT = (float*)d_ws;                 // 524288
    float* sinT = cosT + 524288;                // 524288
    float* Sc   = sinT + 524288;                // 8388608
    float* Zc   = Sc + 8388608;                 // 65536
    bfu* qb   = (bfu*)(Zc + 65536);             // 16777216 bf16
    bfu* kbuf = qb   + 16777216;                // 16777216 bf16
    bfu* vbuf = kbuf + 16777216;                // 16777216 bf16
    bfu* ao   = vbuf + 16777216;                // 16777216 bf16

    rope_table<<<2048, 256, 0, stream>>>(cosT, sinT);
    qkv_rope_gemm<<<dim3(48, 64), 256, 0, stream>>>(x, Wqkv, cosT, sinT, qb, kbuf, vbuf);
    kv_outer<<<512, 256, 0, stream>>>(kbuf, vbuf, Sc, Zc);
    prefix_S<<<2048, 256, 0, stream>>>(Sc);
    prefix_Z<<<16, 256, 0, stream>>>(Zc);
    chunk_fused<<<dim3(2, 512), 256, 0, stream>>>(qb, kbuf, vbuf, Sc, Zc, ao);
    sgemm_abf<<<dim3(16, 64), 256, 0, stream>>>(ao, Wout, out);
}

// Round 3
// 990.328 us; speedup vs baseline: 3.7521x; 3.7521x over previous
//
#include <hip/hip_runtime.h>
#include <cmath>

#define Ss 4096
#define NCh 16
#define CK 256

typedef unsigned short bfu;
typedef __bf16 bf16x8 __attribute__((ext_vector_type(8)));
typedef float f32x4 __attribute__((ext_vector_type(4)));

__device__ __forceinline__ float bf2f(unsigned short u) {
    union { unsigned u32; float f; } v; v.u32 = ((unsigned)u) << 16; return v.f;
}
__device__ __forceinline__ unsigned short f2bf(float f) {
    union { float f; unsigned u; } v; v.f = f;
    unsigned r = v.u + 0x7fff + ((v.u >> 16) & 1);
    return (unsigned short)(r >> 16);
}

// async global->LDS, 16B per lane. lds must be wave-uniform; g is per-lane.
__device__ __forceinline__ void g2l16(void* lds, const void* g) {
    __builtin_amdgcn_global_load_lds(
        (const __attribute__((address_space(1))) void*)g,
        (__attribute__((address_space(3))) void*)lds, 16, 0, 0);
}

// ---------------------------------------------------------------------------
// RoPE tables, compact [s][f] with f = d & 63 (4096 x 64 each).
// ---------------------------------------------------------------------------
__global__ void rope_table(float* __restrict__ cosT, float* __restrict__ sinT) {
    int id = blockIdx.x * 256 + threadIdx.x;      // 262144
    int f = id & 63, s = id >> 6;
    float e = (2.0f * (float)f) / 128.0f;
    float inv = 1.0f / powf(10000.0f, e);
    float ang = (float)s * inv;
    cosT[id] = cosf(ang);
    sinT[id] = sinf(ang);
}

// ---------------------------------------------------------------------------
// fp32 -> bf16 conversion, float4-vectorized grid-stride.
// ---------------------------------------------------------------------------
__global__ void conv_bf16(const float* __restrict__ in, bfu* __restrict__ out, int n4) {
    for (int i = blockIdx.x * 256 + threadIdx.x; i < n4; i += gridDim.x * 256) {
        float4 v = ((const float4*)in)[i];
        ushort4 o;
        o.x = f2bf(v.x); o.y = f2bf(v.y); o.z = f2bf(v.z); o.w = f2bf(v.w);
        ((ushort4*)out)[i] = o;
    }
}

// ---------------------------------------------------------------------------
// bf16 MFMA GEMM, m97 structure: 128x128 tile, BK=64, 4 waves x (64x64),
// global_load_lds width-16 staging, 2 barriers per K-step. K = 2048 fixed.
// A[M][2048], B[N][2048] both K-major bf16. Grid (N/128, M/128), 256 thr.
// EPI=0: fused RoPE+elu+1 epilogue -> qb/kb/vb bf16.  EPI=1: fp32 C store.
// ---------------------------------------------------------------------------
template<int EPI>
__global__ __launch_bounds__(256) void mfma_gemm(
    const bfu* __restrict__ A, const bfu* __restrict__ B,
    const float* __restrict__ cosT, const float* __restrict__ sinT,
    bfu* __restrict__ qb, bfu* __restrict__ kb, bfu* __restrict__ vb,
    float* __restrict__ outF)
{
    __shared__ bfu As[128 * 64];
    __shared__ bfu Bs[128 * 64];
    const int tid = threadIdx.x;
    const int wid = tid >> 6, lane = tid & 63;
    const int wr = wid >> 1, wc = wid & 1;
    const int bm = blockIdx.y * 128, bn = blockIdx.x * 128;
    const int srow = lane >> 3;            // row within 8-row stripe
    const int scol = (lane & 7) * 8;       // bf16 col within 64-wide row
    f32x4 acc[4][4] = {};

    for (int k0 = 0; k0 < 2048; k0 += 64) {
        __syncthreads();   // previous tile fully consumed
#pragma unroll
        for (int i = 0; i < 4; ++i) {
            const int r = i * 32 + wid * 8;            // wave-uniform stripe base
            g2l16(&As[r * 64], A + (size_t)(bm + r + srow) * 2048 + k0 + scol);
            g2l16(&Bs[r * 64], B + (size_t)(bn + r + srow) * 2048 + k0 + scol);
        }
        __syncthreads();   // vmcnt(0) drain + barrier: tile visible
#pragma unroll
        for (int ks = 0; ks < 2; ++ks) {
            bf16x8 af[4], bfr[4];
#pragma unroll
            for (int mi = 0; mi < 4; ++mi)
                af[mi] = *(const bf16x8*)&As[(wr * 64 + mi * 16 + (lane & 15)) * 64 + ks * 32 + (lane >> 4) * 8];
#pragma unroll
            for (int ni = 0; ni < 4; ++ni)
                bfr[ni] = *(const bf16x8*)&Bs[(wc * 64 + ni * 16 + (lane & 15)) * 64 + ks * 32 + (lane >> 4) * 8];
#pragma unroll
            for (int mi = 0; mi < 4; ++mi)
#pragma unroll
                for (int ni = 0; ni < 4; ++ni)
                    acc[mi][ni] = __builtin_amdgcn_mfma_f32_16x16x32_bf16(af[mi], bfr[ni], acc[mi][ni], 0, 0, 0);
        }
    }

    if constexpr (EPI == 0) {
        // C layout (m89-verified): col n = lane&15, row m = (lane>>4)*4 + reg.
        const int part = bn >> 11;             // 0=q 1=k 2=v (uniform per block)
        const int head = (bn >> 7) & 15;       // uniform
        bfu* outp = part == 0 ? qb : part == 1 ? kb : vb;
#pragma unroll
        for (int mi = 0; mi < 4; ++mi) {
            const int m0 = bm + wr * 64 + mi * 16 + ((lane >> 4) << 2);
#pragma unroll
            for (int ni = 0; ni < 4; ++ni) {
                const int d = wc * 64 + ni * 16 + (lane & 15);   // 0..127 within head
                const int f = d & 63;
#pragma unroll
                for (int r = 0; r < 4; ++r) {
                    float v = acc[mi][ni][r];
                    float p = __shfl_xor(v, 1);     // pair partner at d^1 (lane^1)
                    if (part < 2) {
                        const int s = (m0 + r) & 4095;
                        float cc = cosT[s * 64 + f], ssn = sinT[s * 64 + f];
                        float o = (d & 1) ? v * cc + p * ssn : v * cc - p * ssn;
                        v = o > 0.0f ? o + 1.0f : __expf(o);
                    }
                    outp[(size_t)(m0 + r) * 2048 + head * 128 + d] = f2bf(v);
                }
            }
        }
    } else {
#pragma unroll
        for (int mi = 0; mi < 4; ++mi) {
            const int m0 = bm + wr * 64 + mi * 16 + ((lane >> 4) << 2);
#pragma unroll
            for (int ni = 0; ni < 4; ++ni) {
                const int n = bn + wc * 64 + ni * 16 + (lane & 15);
#pragma unroll
                for (int r = 0; r < 4; ++r)
                    outF[(size_t)(m0 + r) * 2048 + n] = acc[mi][ni][r];
            }
        }
    }
}

// ---------------------------------------------------------------------------
// Per (b,h,c): Sc[d][e] = sum_l k[l][d]*v[l][e]; Zc[d] = sum_l k[l][d]
// ---------------------------------------------------------------------------
__global__ __launch_bounds__(256) void kv_outer(const bfu* __restrict__ kbuf,
                                                const bfu* __restrict__ vbuf,
                                                float* __restrict__ Sc, float* __restrict__ Zc)
{
    int batch = blockIdx.x;
    int c = batch & 15, h = (batch >> 4) & 15, b = batch >> 8;
    const int row0 = b*Ss + c*CK;
    const bfu* Kp = kbuf + (size_t)row0 * 2048 + h*128;
    const bfu* Vp = vbuf + (size_t)row0 * 2048 + h*128;
    __shared__ float Ks[8][128];
    __shared__ float Vs[8][128];
    const int tid = threadIdx.x;
    const int row = tid >> 5;
    const int col = (tid & 31) * 4;
    const int ty = tid >> 4, tx = tid & 15;
    float acc[8][8] = {};
    float zacc[8] = {};
    for (int l0 = 0; l0 < CK; l0 += 8) {
        ushort4 k4 = *(const ushort4*)(Kp + (size_t)(l0 + row) * 2048 + col);
        ushort4 v4 = *(const ushort4*)(Vp + (size_t)(l0 + row) * 2048 + col);
        __syncthreads();
        Ks[row][col+0]=bf2f(k4.x); Ks[row][col+1]=bf2f(k4.y); Ks[row][col+2]=bf2f(k4.z); Ks[row][col+3]=bf2f(k4.w);
        Vs[row][col+0]=bf2f(v4.x); Vs[row][col+1]=bf2f(v4.y); Vs[row][col+2]=bf2f(v4.z); Vs[row][col+3]=bf2f(v4.w);
        __syncthreads();
#pragma unroll
        for (int kk = 0; kk < 8; ++kk) {
            float4 a0 = *(const float4*)&Ks[kk][ty*8];
            float4 a1 = *(const float4*)&Ks[kk][ty*8+4];
            float4 b0 = *(const float4*)&Vs[kk][tx*8];
            float4 b1 = *(const float4*)&Vs[kk][tx*8+4];
            float av[8] = {a0.x,a0.y,a0.z,a0.w,a1.x,a1.y,a1.z,a1.w};
            float bv[8] = {b0.x,b0.y,b0.z,b0.w,b1.x,b1.y,b1.z,b1.w};
#pragma unroll
            for (int i=0;i<8;i++) {
#pragma unroll
                for (int j=0;j<8;j++) acc[i][j] += av[i]*bv[j];
                if (tx == 0) zacc[i] += av[i];
            }
        }
    }
    float* Sout = Sc + (size_t)batch * 16384;
#pragma unroll
    for (int i=0;i<8;i++) {
        float* crow = Sout + (size_t)(ty*8+i)*128 + tx*8;
        *(float4*)crow     = make_float4(acc[i][0],acc[i][1],acc[i][2],acc[i][3]);
        *(float4*)(crow+4) = make_float4(acc[i][4],acc[i][5],acc[i][6],acc[i][7]);
    }
    if (tx == 0) {
#pragma unroll
        for (int i=0;i<8;i++) Zc[(size_t)batch*128 + ty*8 + i] = zacc[i];
    }
}

// ---------------------------------------------------------------------------
// Exclusive prefix over chunks (16), in place.
// ---------------------------------------------------------------------------
__global__ void prefix_S(float* __restrict__ Sc) {
    size_t idx = (size_t)blockIdx.x * 256 + threadIdx.x;  // 32*16384
    size_t bh = idx >> 14;
    size_t de = idx & 16383;
    float* p = Sc + bh * (size_t)NCh * 16384 + de;
    float run = 0.0f;
#pragma unroll
    for (int c = 0; c < NCh; ++c) {
        float t = p[(size_t)c * 16384];
        p[(size_t)c * 16384] = run;
        run += t;
    }
}
__global__ void prefix_Z(float* __restrict__ Zc) {
    size_t idx = (size_t)blockIdx.x * 256 + threadIdx.x;  // 32*128
    size_t bh = idx >> 7;
    size_t d = idx & 127;
    float* p = Zc + bh * (size_t)NCh * 128 + d;
    float run = 0.0f;
#pragma unroll
    for (int c = 0; c < NCh; ++c) {
        float t = p[(size_t)c * 128];
        p[(size_t)c * 128] = run;
        run += t;
    }
}

// ---------------------------------------------------------------------------
// Fused chunk attention (unchanged, verified in round 2).
// ---------------------------------------------------------------------------
__global__ __launch_bounds__(256) void chunk_fused(
    const bfu* __restrict__ qb, const bfu* __restrict__ kbuf, const bfu* __restrict__ vbuf,
    const float* __restrict__ Sc, const float* __restrict__ Zc, bfu* __restrict__ ao)
{
    __shared__ float attkm[128][132];
    __shared__ float As[8][128];
    __shared__ float Bs[8][128];
    __shared__ float Zs[128];
    const int half = blockIdx.x, batch = blockIdx.y;
    const int c = batch & 15, h = (batch >> 4) & 15, b = batch >> 8;
    const int row0 = b*Ss + c*CK;
    const int tid = threadIdx.x;
    const int lrow = tid >> 1;
    const int lk   = (tid & 1) * 4;
    const int brow = tid >> 5;
    const int bcol = (tid & 31) * 4;
    const int ty = tid >> 4, tx = tid & 15;
    float num[8][8] = {};
    float den[8] = {};
    if (tid < 128) Zs[tid] = Zc[(size_t)batch * 128 + tid];
    const bfu* qbase = qb + (size_t)(row0 + half*128) * 2048 + h*128;

    for (int kb_ = 0; kb_ <= half; ++kb_) {
        float acc[8][8] = {};
        const bfu* kbase = kbuf + (size_t)(row0 + kb_*128) * 2048 + h*128;
        for (int k0 = 0; k0 < 128; k0 += 8) {
            ushort4 qa = *(const ushort4*)(qbase + (size_t)lrow * 2048 + k0 + lk);
            ushort4 ka = *(const ushort4*)(kbase + (size_t)lrow * 2048 + k0 + lk);
            __syncthreads();
            As[lk+0][lrow]=bf2f(qa.x); As[lk+1][lrow]=bf2f(qa.y); As[lk+2][lrow]=bf2f(qa.z); As[lk+3][lrow]=bf2f(qa.w);
            Bs[lk+0][lrow]=bf2f(ka.x); Bs[lk+1][lrow]=bf2f(ka.y); Bs[lk+2][lrow]=bf2f(ka.z); Bs[lk+3][lrow]=bf2f(ka.w);
            __syncthreads();
#pragma unroll
            for (int kk = 0; kk < 8; ++kk) {
                float4 a0 = *(const float4*)&As[kk][ty*8];
                float4 a1 = *(const float4*)&As[kk][ty*8+4];
                float4 b0 = *(const float4*)&Bs[kk][tx*8];
                float4 b1 = *(const float4*)&Bs[kk][tx*8+4];
                float av[8] = {a0.x,a0.y,a0.z,a0.w,a1.x,a1.y,a1.z,a1.w};
                float bv[8] = {b0.x,b0.y,b0.z,b0.w,b1.x,b1.y,b1.z,b1.w};
#pragma unroll
                for (int i=0;i<8;i++)
#pragma unroll
                    for (int j=0;j<8;j++) acc[i][j] += av[i]*bv[j];
            }
        }
        const bool needmask = (kb_ == half);
#pragma unroll
        for (int j=0;j<8;j++) {
            int m = tx*8 + j;
            int mg = kb_*128 + m;
            float o[8];
#pragma unroll
            for (int i=0;i<8;i++) {
                int lg = half*128 + ty*8 + i;
                o[i] = (!needmask || lg >= mg) ? acc[i][j] : 0.0f;
            }
            *(float4*)&attkm[m][ty*8]   = make_float4(o[0],o[1],o[2],o[3]);
            *(float4*)&attkm[m][ty*8+4] = make_float4(o[4],o[5],o[6],o[7]);
        }
        const bfu* vbase = vbuf + (size_t)(row0 + kb_*128) * 2048 + h*128;
        for (int k0 = 0; k0 < 128; k0 += 8) {
            ushort4 va = *(const ushort4*)(vbase + (size_t)(k0 + brow) * 2048 + bcol);
            __syncthreads();
            Bs[brow][bcol+0]=bf2f(va.x); Bs[brow][bcol+1]=bf2f(va.y); Bs[brow][bcol+2]=bf2f(va.z); Bs[brow][bcol+3]=bf2f(va.w);
            __syncthreads();
#pragma unroll
            for (int kk = 0; kk < 8; ++kk) {
                float4 a0 = *(const float4*)&attkm[k0+kk][ty*8];
                float4 a1 = *(const float4*)&attkm[k0+kk][ty*8+4];
                float4 b0 = *(const float4*)&Bs[kk][tx*8];
                float4 b1 = *(const float4*)&Bs[kk][tx*8+4];
                float av[8] = {a0.x,a0.y,a0.z,a0.w,a1.x,a1.y,a1.z,a1.w};
                float bv[8] = {b0.x,b0.y,b0.z,b0.w,b1.x,b1.y,b1.z,b1.w};
#pragma unroll
                for (int i=0;i<8;i++) {
                    den[i] += av[i];
#pragma unroll
                    for (int j=0;j<8;j++) num[i][j] += av[i]*bv[j];
                }
            }
        }
    }
    const float* Sbase = Sc + (size_t)batch * 16384;
    for (int k0 = 0; k0 < 128; k0 += 8) {
        ushort4 qa = *(const ushort4*)(qbase + (size_t)lrow * 2048 + k0 + lk);
        float4 sb = *(const float4*)(Sbase + (size_t)(k0 + brow) * 128 + bcol);
        __syncthreads();
        As[lk+0][lrow]=bf2f(qa.x); As[lk+1][lrow]=bf2f(qa.y); As[lk+2][lrow]=bf2f(qa.z); As[lk+3][lrow]=bf2f(qa.w);
        *(float4*)&Bs[brow][bcol] = sb;
        __syncthreads();
#pragma unroll
        for (int kk = 0; kk < 8; ++kk) {
            float4 a0 = *(const float4*)&As[kk][ty*8];
            float4 a1 = *(const float4*)&As[kk][ty*8+4];
            float4 b0 = *(const float4*)&Bs[kk][tx*8];
            float4 b1 = *(const float4*)&Bs[kk][tx*8+4];
            float av[8] = {a0.x,a0.y,a0.z,a0.w,a1.x,a1.y,a1.z,a1.w};
            float bv[8] = {b0.x,b0.y,b0.z,b0.w,b1.x,b1.y,b1.z,b1.w};
            float zv = Zs[k0+kk];
#pragma unroll
            for (int i=0;i<8;i++) {
                den[i] += av[i]*zv;
#pragma unroll
                for (int j=0;j<8;j++) num[i][j] += av[i]*bv[j];
            }
        }
    }
    bfu* aop = ao + (size_t)(row0 + half*128) * 2048 + h*128;
#pragma unroll
    for (int i=0;i<8;i++) {
        float dv = den[i] > 1e-6f ? den[i] : 1e-6f;
        float inv = 1.0f / dv;
        bfu t[8];
#pragma unroll
        for (int j=0;j<8;j++) t[j] = f2bf(num[i][j]*inv);
        *(uint4*)(aop + (size_t)(ty*8+i)*2048 + tx*8) = *(uint4*)t;
    }
}

// ---------------------------------------------------------------------------
extern "C" void kernel_launch(void* const* d_in, const int* in_sizes, int n_in,
                              void* d_out, int out_size, void* d_ws, size_t ws_size,
                              hipStream_t stream)
{
    const float* x    = (const float*)d_in[0];
    const float* Wqkv = (const float*)d_in[1];
    const float* Wout = (const float*)d_in[2];
    float* out = (float*)d_out;
    char* ws = (char*)d_ws;

    // byte layout (~195 MB), with region reuse:
    //   region A [0, 32M): xb (bf16 x), later wob (bf16 Wout)
    //   region B [32M, 64M): wqb (bf16 Wqkv), later ao (bf16 attn out)
    bfu* xb   = (bfu*)(ws);                          // 16,777,216 bf16
    bfu* wob  = (bfu*)(ws);                          //  4,194,304 bf16 (aliases xb, written after qkv gemm)
    bfu* wqb  = (bfu*)(ws + 33554432);               // 12,582,912 bf16
    bfu* ao   = (bfu*)(ws + 33554432);               // 16,777,216 bf16 (aliases wqb, written after qkv gemm)
    float* cosT = (float*)(ws + 67108864);           // 262,144 f32
    float* sinT = (float*)(ws + 68157440);           // 262,144 f32
    float* Sc   = (float*)(ws + 69206016);           // 8,388,608 f32
    float* Zc   = (float*)(ws + 102760448);          // 65,536 f32
    bfu* qb   = (bfu*)(ws + 103022592);              // 16,777,216 bf16
    bfu* kb   = (bfu*)(ws + 136577024);              // 16,777,216 bf16
    bfu* vb   = (bfu*)(ws + 170131456);              // 16,777,216 bf16
    // end: 203,685,888 bytes

    rope_table<<<1024, 256, 0, stream>>>(cosT, sinT);
    conv_bf16<<<2048, 256, 0, stream>>>(x,    xb,  4194304);
    conv_bf16<<<2048, 256, 0, stream>>>(Wqkv, wqb, 3145728);
    // qkv = x @ Wqkv^T with fused RoPE+elu+1, bf16 out
    mfma_gemm<0><<<dim3(48, 64), 256, 0, stream>>>(xb, wqb, cosT, sinT, qb, kb, vb, nullptr);
    conv_bf16<<<1024, 256, 0, stream>>>(Wout, wob, 1048576);   // xb dead now
    kv_outer<<<512, 256, 0, stream>>>(kb, vb, Sc, Zc);
    prefix_S<<<2048, 256, 0, stream>>>(Sc);
    prefix_Z<<<16, 256, 0, stream>>>(Zc);
    chunk_fused<<<dim3(2, 512), 256, 0, stream>>>(qb, kb, vb, Sc, Zc, ao);  // wqb dead now
    // out = ao @ Wout^T, fp32 store
    mfma_gemm<1><<<dim3(16, 64), 256, 0, stream>>>(ao, wob, nullptr, nullptr, nullptr, nullptr, nullptr, out);
}

// Round 4
// 591.071 us; speedup vs baseline: 6.2865x; 1.6755x over previous
//
#include <hip/hip_runtime.h>
#include <cmath>

#define Ss 4096
#define NCh 16
#define CK 256

typedef unsigned short bfu;
typedef __bf16 bf16x8 __attribute__((ext_vector_type(8)));
typedef float f32x4 __attribute__((ext_vector_type(4)));
typedef unsigned short u16x8 __attribute__((ext_vector_type(8)));

__device__ __forceinline__ float bf2f(unsigned short u) {
    union { unsigned u32; float f; } v; v.u32 = ((unsigned)u) << 16; return v.f;
}
__device__ __forceinline__ unsigned short f2bf(float f) {
    union { float f; unsigned u; } v; v.f = f;
    unsigned r = v.u + 0x7fff + ((v.u >> 16) & 1);
    return (unsigned short)(r >> 16);
}

// async global->LDS, 16B per lane. lds base wave-uniform; g per-lane.
__device__ __forceinline__ void g2l16(void* lds, const void* g) {
    __builtin_amdgcn_global_load_lds(
        (const __attribute__((address_space(1))) void*)g,
        (__attribute__((address_space(3))) void*)lds, 16, 0, 0);
}

// ---------------------------------------------------------------------------
// RoPE tables, compact [s][f], f = d & 63 (4096 x 64 each).
// ---------------------------------------------------------------------------
__global__ void rope_table(float* __restrict__ cosT, float* __restrict__ sinT) {
    int id = blockIdx.x * 256 + threadIdx.x;      // 262144
    int f = id & 63, s = id >> 6;
    float e = (2.0f * (float)f) / 128.0f;
    float inv = 1.0f / powf(10000.0f, e);
    float ang = (float)s * inv;
    cosT[id] = cosf(ang);
    sinT[id] = sinf(ang);
}

// ---------------------------------------------------------------------------
// fp32 -> bf16 conversion, float4-vectorized grid-stride.
// ---------------------------------------------------------------------------
__global__ void conv_bf16(const float* __restrict__ in, bfu* __restrict__ out, int n4) {
    for (int i = blockIdx.x * 256 + threadIdx.x; i < n4; i += gridDim.x * 256) {
        float4 v = ((const float4*)in)[i];
        ushort4 o;
        o.x = f2bf(v.x); o.y = f2bf(v.y); o.z = f2bf(v.z); o.w = f2bf(v.w);
        ((ushort4*)out)[i] = o;
    }
}

// ---------------------------------------------------------------------------
// bf16 MFMA GEMM (m97 structure): 128x128 tile, BK=64, 4 waves x (64x64).
// A[M][2048], B[N][2048] K-major bf16. Grid (N/128, M/128), 256 thr.
// EPI=0: fused RoPE+elu+1; writes qb,kb (seq-major) and kT,vT (feature-major
//        [b][h][d][4096]).  EPI=1: fp32 C store.
// ---------------------------------------------------------------------------
template<int EPI>
__global__ __launch_bounds__(256) void mfma_gemm(
    const bfu* __restrict__ A, const bfu* __restrict__ B,
    const float* __restrict__ cosT, const float* __restrict__ sinT,
    bfu* __restrict__ qb, bfu* __restrict__ kb,
    bfu* __restrict__ kT, bfu* __restrict__ vT,
    float* __restrict__ outF)
{
    __shared__ bfu As[128 * 64];
    __shared__ bfu Bs[128 * 64];
    const int tid = threadIdx.x;
    const int wid = tid >> 6, lane = tid & 63;
    const int wr = wid >> 1, wc = wid & 1;
    const int bm = blockIdx.y * 128, bn = blockIdx.x * 128;
    const int srow = lane >> 3;            // row within 8-row stripe (128B rows)
    const int scol = (lane & 7) * 8;
    f32x4 acc[4][4] = {};

    for (int k0 = 0; k0 < 2048; k0 += 64) {
        __syncthreads();
#pragma unroll
        for (int i = 0; i < 4; ++i) {
            const int r = i * 32 + wid * 8;
            g2l16(&As[r * 64], A + (size_t)(bm + r + srow) * 2048 + k0 + scol);
            g2l16(&Bs[r * 64], B + (size_t)(bn + r + srow) * 2048 + k0 + scol);
        }
        __syncthreads();
#pragma unroll
        for (int ks = 0; ks < 2; ++ks) {
            bf16x8 af[4], bfr[4];
#pragma unroll
            for (int mi = 0; mi < 4; ++mi)
                af[mi] = *(const bf16x8*)&As[(wr * 64 + mi * 16 + (lane & 15)) * 64 + ks * 32 + (lane >> 4) * 8];
#pragma unroll
            for (int ni = 0; ni < 4; ++ni)
                bfr[ni] = *(const bf16x8*)&Bs[(wc * 64 + ni * 16 + (lane & 15)) * 64 + ks * 32 + (lane >> 4) * 8];
#pragma unroll
            for (int mi = 0; mi < 4; ++mi)
#pragma unroll
                for (int ni = 0; ni < 4; ++ni)
                    acc[mi][ni] = __builtin_amdgcn_mfma_f32_16x16x32_bf16(af[mi], bfr[ni], acc[mi][ni], 0, 0, 0);
        }
    }

    if constexpr (EPI == 0) {
        const int part = bn >> 11;             // 0=q 1=k 2=v (uniform)
        const int headcol = bn & 2047;         // head*128 (uniform)
        const int head = headcol >> 7;
#pragma unroll
        for (int mi = 0; mi < 4; ++mi) {
            const int m0 = bm + wr * 64 + mi * 16 + ((lane >> 4) << 2);
            const int bq = m0 >> 12;           // batch b
            const int sloc = m0 & 4095;
#pragma unroll
            for (int ni = 0; ni < 4; ++ni) {
                const int d = wc * 64 + ni * 16 + (lane & 15);
                const int f = d & 63;
                float vv[4];
#pragma unroll
                for (int r = 0; r < 4; ++r) {
                    float v = acc[mi][ni][r];
                    float p = __shfl_xor(v, 1);      // partner d^1 (lane^1)
                    if (part < 2) {
                        const int s = (m0 + r) & 4095;
                        float cc = cosT[s * 64 + f], sn = sinT[s * 64 + f];
                        float o = (d & 1) ? v * cc + p * sn : v * cc - p * sn;
                        v = o > 0.0f ? o + 1.0f : __expf(o);
                    }
                    vv[r] = v;
                }
                if (part == 0) {
#pragma unroll
                    for (int r = 0; r < 4; ++r)
                        qb[(size_t)(m0 + r) * 2048 + headcol + d] = f2bf(vv[r]);
                } else if (part == 1) {
#pragma unroll
                    for (int r = 0; r < 4; ++r)
                        kb[(size_t)(m0 + r) * 2048 + headcol + d] = f2bf(vv[r]);
                    ushort4 t4;
                    t4.x = f2bf(vv[0]); t4.y = f2bf(vv[1]); t4.z = f2bf(vv[2]); t4.w = f2bf(vv[3]);
                    *(ushort4*)(kT + ((size_t)(bq * 16 + head) * 128 + d) * 4096 + sloc) = t4;
                } else {
                    ushort4 t4;
                    t4.x = f2bf(vv[0]); t4.y = f2bf(vv[1]); t4.z = f2bf(vv[2]); t4.w = f2bf(vv[3]);
                    *(ushort4*)(vT + ((size_t)(bq * 16 + head) * 128 + d) * 4096 + sloc) = t4;
                }
            }
        }
    } else {
#pragma unroll
        for (int mi = 0; mi < 4; ++mi) {
            const int m0 = bm + wr * 64 + mi * 16 + ((lane >> 4) << 2);
#pragma unroll
            for (int ni = 0; ni < 4; ++ni) {
                const int n = bn + wc * 64 + ni * 16 + (lane & 15);
#pragma unroll
                for (int r = 0; r < 4; ++r)
                    outF[(size_t)(m0 + r) * 2048 + n] = acc[mi][ni][r];
            }
        }
    }
}

// ---------------------------------------------------------------------------
// Per (b,h,c): S^T[e][d] = P(vT, kT) over chunk (K=256), + Zc[d] = sum_l k[l][d].
// Output Scb bf16 [batch][e][d]. Grid 512, 256 thr.
// ---------------------------------------------------------------------------
__global__ __launch_bounds__(256) void kv_outer_mfma(
    const bfu* __restrict__ vT, const bfu* __restrict__ kT,
    bfu* __restrict__ Scb, float* __restrict__ Zc)
{
    __shared__ bfu As[128 * 64];   // vT tile (e rows)
    __shared__ bfu Bs[128 * 64];   // kT tile (d rows)
    __shared__ float zS[128][2];
    const int batch = blockIdx.x;
    const int c = batch & 15, h = (batch >> 4) & 15, b = batch >> 8;
    const size_t fbase = (size_t)(b * 16 + h) * 128 * 4096 + c * 256;
    const int tid = threadIdx.x, wid = tid >> 6, lane = tid & 63;
    const int wr = wid >> 1, wc = wid & 1;
    const int srow = lane >> 3, scol = (lane & 7) * 8;
    f32x4 acc[4][4] = {};
    float zreg = 0.0f;
    const int zd = tid >> 1, zo = (tid & 1) * 32;

    for (int k0 = 0; k0 < 256; k0 += 64) {
        __syncthreads();
#pragma unroll
        for (int i = 0; i < 4; ++i) {
            const int r = i * 32 + wid * 8;
            g2l16(&As[r * 64], vT + fbase + (size_t)(r + srow) * 4096 + k0 + scol);
            g2l16(&Bs[r * 64], kT + fbase + (size_t)(r + srow) * 4096 + k0 + scol);
        }
        __syncthreads();
#pragma unroll
        for (int ks = 0; ks < 2; ++ks) {
            bf16x8 af[4], bfr[4];
#pragma unroll
            for (int mi = 0; mi < 4; ++mi)
                af[mi] = *(const bf16x8*)&As[(wr * 64 + mi * 16 + (lane & 15)) * 64 + ks * 32 + (lane >> 4) * 8];
#pragma unroll
            for (int ni = 0; ni < 4; ++ni)
                bfr[ni] = *(const bf16x8*)&Bs[(wc * 64 + ni * 16 + (lane & 15)) * 64 + ks * 32 + (lane >> 4) * 8];
#pragma unroll
            for (int mi = 0; mi < 4; ++mi)
#pragma unroll
                for (int ni = 0; ni < 4; ++ni)
                    acc[mi][ni] = __builtin_amdgcn_mfma_f32_16x16x32_bf16(af[mi], bfr[ni], acc[mi][ni], 0, 0, 0);
        }
        // Z partial sums from kT tile (rows = d)
#pragma unroll
        for (int j = 0; j < 32; ++j) zreg += bf2f(Bs[zd * 64 + zo + j]);
    }
    zS[zd][tid & 1] = zreg;
    __syncthreads();
    if (tid < 128) Zc[(size_t)batch * 128 + tid] = zS[tid][0] + zS[tid][1];
    bfu* Sout = Scb + (size_t)batch * 16384;
#pragma unroll
    for (int mi = 0; mi < 4; ++mi)
#pragma unroll
        for (int ni = 0; ni < 4; ++ni) {
            const int d = wc * 64 + ni * 16 + (lane & 15);
#pragma unroll
            for (int r = 0; r < 4; ++r) {
                const int e = wr * 64 + mi * 16 + ((lane >> 4) << 2) + r;
                Sout[e * 128 + d] = f2bf(acc[mi][ni][r]);
            }
        }
}

// ---------------------------------------------------------------------------
// Exclusive prefixes over chunks (in place). Scb bf16 (fp32 running sum).
// ---------------------------------------------------------------------------
__global__ void prefix_Sb(bfu* __restrict__ Scb) {
    size_t idx = (size_t)blockIdx.x * 256 + threadIdx.x;  // 32*16384
    size_t bh = idx >> 14, de = idx & 16383;
    bfu* p = Scb + bh * (size_t)NCh * 16384 + de;
    float run = 0.0f;
#pragma unroll
    for (int c = 0; c < NCh; ++c) {
        float t = bf2f(p[(size_t)c * 16384]);
        p[(size_t)c * 16384] = f2bf(run);
        run += t;
    }
}
__global__ void prefix_Z(float* __restrict__ Zc) {
    size_t idx = (size_t)blockIdx.x * 256 + threadIdx.x;  // 32*128
    size_t bh = idx >> 7, d = idx & 127;
    float* p = Zc + bh * (size_t)NCh * 128 + d;
    float run = 0.0f;
#pragma unroll
    for (int c = 0; c < NCh; ++c) {
        float t = p[(size_t)c * 128];
        p[(size_t)c * 128] = run;
        run += t;
    }
}

// ---------------------------------------------------------------------------
// MFMA chunk attention. Grid (2 halves, 512 batch), 256 thr / 4 waves (2x2).
// Per block: 128 q rows. att = P(q,k) masked -> bf16 LDS (XOR swizzle);
// num += P(att, vT); num += P(q, S^T); den = rowsum(att) + q.Z.
// ---------------------------------------------------------------------------
__global__ __launch_bounds__(256) void chunk_mfma(
    const bfu* __restrict__ qb, const bfu* __restrict__ kb,
    const bfu* __restrict__ vT, const bfu* __restrict__ Scb,
    const float* __restrict__ Zc, bfu* __restrict__ ao)
{
    __shared__ bfu shrd[16384];    // k tile [m][128] / vT tile [e][128] / S^T tile [e][128]
    __shared__ bfu attL[16384];    // att [l][m] bf16, byte ^ ((l&7)<<4)
    __shared__ float Zs[128];
    __shared__ float denS[128][2];
    const int half = blockIdx.x, batch = blockIdx.y;
    const int c = batch & 15, h = (batch >> 4) & 15, b = batch >> 8;
    const int row0 = b * Ss + c * CK;
    const int tid = threadIdx.x, wid = tid >> 6, lane = tid & 63;
    const int wr = wid >> 1, wc = wid & 1;
    const int sr = lane >> 4, sc8 = (lane & 15) * 8;   // 256B-row staging
    if (tid < 128) Zs[tid] = Zc[(size_t)batch * 128 + tid];

    // q fragments (A operand, rows l, K=d=128), kept in registers
    bf16x8 qf[4][4];
    {
        const bfu* qrow = qb + (size_t)(row0 + half * 128 + wr * 64 + (lane & 15)) * 2048
                          + h * 128 + (lane >> 4) * 8;
#pragma unroll
        for (int mi = 0; mi < 4; ++mi)
#pragma unroll
            for (int ks = 0; ks < 4; ++ks)
                qf[mi][ks] = *(const bf16x8*)(qrow + (size_t)mi * 16 * 2048 + ks * 32);
    }
    f32x4 num[4][4] = {};
    float den_reg = 0.0f;
    const int dl = tid >> 1, dc0 = (tid & 1) * 64;

    for (int kb_ = 0; kb_ <= half; ++kb_) {
        __syncthreads();                     // prev consumers done
#pragma unroll
        for (int i = 0; i < 8; ++i) {        // stage k tile [m][128]
            const int r = i * 16 + wid * 4;
            g2l16(&shrd[r * 128], kb + (size_t)(row0 + kb_ * 128 + r + sr) * 2048 + h * 128 + sc8);
        }
        __syncthreads();                     // k visible
        f32x4 attacc[4][4] = {};
#pragma unroll
        for (int ks = 0; ks < 4; ++ks) {
            bf16x8 bfr[4];
#pragma unroll
            for (int ni = 0; ni < 4; ++ni)
                bfr[ni] = *(const bf16x8*)&shrd[(wc * 64 + ni * 16 + (lane & 15)) * 128 + ks * 32 + (lane >> 4) * 8];
#pragma unroll
            for (int mi = 0; mi < 4; ++mi)
#pragma unroll
                for (int ni = 0; ni < 4; ++ni)
                    attacc[mi][ni] = __builtin_amdgcn_mfma_f32_16x16x32_bf16(qf[mi][ks], bfr[ni], attacc[mi][ni], 0, 0, 0);
        }
        __syncthreads();                     // k consumed
#pragma unroll
        for (int i = 0; i < 8; ++i) {        // stage vT tile [e][128] (same buffer)
            const int r = i * 16 + wid * 4;
            g2l16(&shrd[r * 128],
                  vT + ((size_t)(b * 16 + h) * 128 + r + sr) * 4096 + c * 256 + kb_ * 128 + sc8);
        }
        // mask + write att tile (bf16, swizzled)
        const bool needmask = (kb_ == half);
#pragma unroll
        for (int mi = 0; mi < 4; ++mi)
#pragma unroll
            for (int ni = 0; ni < 4; ++ni) {
                const int l0 = wr * 64 + mi * 16 + ((lane >> 4) << 2);
                const int m = wc * 64 + ni * 16 + (lane & 15);
#pragma unroll
                for (int r = 0; r < 4; ++r) {
                    const int l = l0 + r;
                    float v = attacc[mi][ni][r];
                    if (needmask && (half * 128 + l) < (kb_ * 128 + m)) v = 0.0f;
                    const int byte = (l * 256 + m * 2) ^ ((l & 7) << 4);
                    *(bfu*)((char*)attL + byte) = f2bf(v);
                }
            }
        __syncthreads();                     // vT + att visible
#pragma unroll
        for (int ks = 0; ks < 4; ++ks) {     // num += P(att, vT)
            bf16x8 af[4], bfr[4];
#pragma unroll
            for (int mi = 0; mi < 4; ++mi) {
                const int l = wr * 64 + mi * 16 + (lane & 15);
                const int byte = (l * 256 + (ks * 32 + (lane >> 4) * 8) * 2) ^ ((l & 7) << 4);
                af[mi] = *(const bf16x8*)((const char*)attL + byte);
            }
#pragma unroll
            for (int ni = 0; ni < 4; ++ni)
                bfr[ni] = *(const bf16x8*)&shrd[(wc * 64 + ni * 16 + (lane & 15)) * 128 + ks * 32 + (lane >> 4) * 8];
#pragma unroll
            for (int mi = 0; mi < 4; ++mi)
#pragma unroll
                for (int ni = 0; ni < 4; ++ni)
                    num[mi][ni] = __builtin_amdgcn_mfma_f32_16x16x32_bf16(af[mi], bfr[ni], num[mi][ni], 0, 0, 0);
        }
        // den += rowsum of masked att (row dl, 64-col half dc0)
#pragma unroll
        for (int j8 = 0; j8 < 8; ++j8) {
            const int byte = (dl * 256 + (dc0 + j8 * 8) * 2) ^ ((dl & 7) << 4);
            u16x8 a = *(const u16x8*)((const char*)attL + byte);
#pragma unroll
            for (int jj = 0; jj < 8; ++jj) den_reg += bf2f(a[jj]);
        }
    }
    __syncthreads();                         // PV done with shrd
#pragma unroll
    for (int i = 0; i < 8; ++i) {            // stage S^T tile [e][128]
        const int r = i * 16 + wid * 4;
        g2l16(&shrd[r * 128], Scb + (size_t)batch * 16384 + (size_t)(r + sr) * 128 + sc8);
    }
    __syncthreads();
#pragma unroll
    for (int ks = 0; ks < 4; ++ks) {         // num += P(q, S^T)
        bf16x8 bfr[4];
#pragma unroll
        for (int ni = 0; ni < 4; ++ni)
            bfr[ni] = *(const bf16x8*)&shrd[(wc * 64 + ni * 16 + (lane & 15)) * 128 + ks * 32 + (lane >> 4) * 8];
#pragma unroll
        for (int mi = 0; mi < 4; ++mi)
#pragma unroll
            for (int ni = 0; ni < 4; ++ni)
                num[mi][ni] = __builtin_amdgcn_mfma_f32_16x16x32_bf16(qf[mi][ks], bfr[ni], num[mi][ni], 0, 0, 0);
    }
    // den += q . Z  (row dl, 64-col half dc0)
    {
        const bfu* qrow = qb + (size_t)(row0 + half * 128 + dl) * 2048 + h * 128 + dc0;
#pragma unroll
        for (int j8 = 0; j8 < 8; ++j8) {
            u16x8 a = *(const u16x8*)(qrow + j8 * 8);
#pragma unroll
            for (int jj = 0; jj < 8; ++jj) den_reg += bf2f(a[jj]) * Zs[dc0 + j8 * 8 + jj];
        }
    }
    denS[dl][tid & 1] = den_reg;
    __syncthreads();
    bfu* aop = ao + (size_t)(row0 + half * 128) * 2048 + h * 128;
#pragma unroll
    for (int mi = 0; mi < 4; ++mi)
#pragma unroll
        for (int ni = 0; ni < 4; ++ni) {
            const int e = wc * 64 + ni * 16 + (lane & 15);
#pragma unroll
            for (int r = 0; r < 4; ++r) {
                const int l = wr * 64 + mi * 16 + ((lane >> 4) << 2) + r;
                float dv = denS[l][0] + denS[l][1];
                dv = dv > 1e-6f ? dv : 1e-6f;
                aop[(size_t)l * 2048 + e] = f2bf(num[mi][ni][r] / dv);
            }
        }
}

// ---------------------------------------------------------------------------
extern "C" void kernel_launch(void* const* d_in, const int* in_sizes, int n_in,
                              void* d_out, int out_size, void* d_ws, size_t ws_size,
                              hipStream_t stream)
{
    const float* x    = (const float*)d_in[0];
    const float* Wqkv = (const float*)d_in[1];
    const float* Wout = (const float*)d_in[2];
    float* out = (float*)d_out;
    char* ws = (char*)d_ws;

    // byte layout (~202.3 MB total):
    bfu* xb   = (bfu*)(ws);                    // 16,777,216 elems; ao aliases after qkv gemm
    bfu* ao   = (bfu*)(ws);
    bfu* wqb  = (bfu*)(ws + 33554432);         // 12,582,912 elems; wob aliases after
    bfu* wob  = (bfu*)(ws + 33554432);         //  4,194,304 elems
    float* cosT = (float*)(ws + 58720256);     // 262,144
    float* sinT = (float*)(ws + 59768832);     // 262,144
    bfu* Scb  = (bfu*)(ws + 60817408);         // 8,388,608 elems (bf16 S^T states)
    float* Zc = (float*)(ws + 77594624);       // 65,536
    bfu* qb   = (bfu*)(ws + 77856768);         // 16,777,216
    bfu* kb   = (bfu*)(ws + 111411200);        // 16,777,216
    bfu* kTb  = (bfu*)(ws + 144965632);        // 16,777,216
    bfu* vTb  = (bfu*)(ws + 178520064);        // 16,777,216  (end 212,074,496)

    rope_table<<<1024, 256, 0, stream>>>(cosT, sinT);
    conv_bf16<<<2048, 256, 0, stream>>>(x,    xb,  4194304);
    conv_bf16<<<2048, 256, 0, stream>>>(Wqkv, wqb, 3145728);
    mfma_gemm<0><<<dim3(48, 64), 256, 0, stream>>>(xb, wqb, cosT, sinT, qb, kb, kTb, vTb, nullptr);
    conv_bf16<<<1024, 256, 0, stream>>>(Wout, wob, 1048576);   // xb dead now
    kv_outer_mfma<<<512, 256, 0, stream>>>(vTb, kTb, Scb, Zc);
    prefix_Z<<<16, 256, 0, stream>>>(Zc);
    prefix_Sb<<<2048, 256, 0, stream>>>(Scb);
    chunk_mfma<<<dim3(2, 512), 256, 0, stream>>>(qb, kb, vTb, Scb, Zc, ao);
    mfma_gemm<1><<<dim3(16, 64), 256, 0, stream>>>(ao, wob, nullptr, nullptr, nullptr, nullptr, nullptr, nullptr, out);
}

// Round 5
// 513.060 us; speedup vs baseline: 7.2424x; 1.1520x over previous
//
#include <hip/hip_runtime.h>
#include <cmath>

#define Ss 4096
#define NCh 16
#define CK 256

typedef unsigned short bfu;
typedef __bf16 bf16x8 __attribute__((ext_vector_type(8)));
typedef float f32x4 __attribute__((ext_vector_type(4)));
typedef unsigned short u16x8 __attribute__((ext_vector_type(8)));

__device__ __forceinline__ float bf2f(unsigned short u) {
    union { unsigned u32; float f; } v; v.u32 = ((unsigned)u) << 16; return v.f;
}
__device__ __forceinline__ unsigned short f2bf(float f) {
    union { float f; unsigned u; } v; v.f = f;
    unsigned r = v.u + 0x7fff + ((v.u >> 16) & 1);
    return (unsigned short)(r >> 16);
}

// async global->LDS, 16B per lane. lds base wave-uniform; g per-lane.
__device__ __forceinline__ void g2l16(void* lds, const void* g) {
    __builtin_amdgcn_global_load_lds(
        (const __attribute__((address_space(1))) void*)g,
        (__attribute__((address_space(3))) void*)lds, 16, 0, 0);
}

// ---------------------------------------------------------------------------
// RoPE tables, compact [s][f], f = d & 63 (4096 x 64 each).
// ---------------------------------------------------------------------------
__global__ void rope_table(float* __restrict__ cosT, float* __restrict__ sinT) {
    int id = blockIdx.x * 256 + threadIdx.x;      // 262144
    int f = id & 63, s = id >> 6;
    float e = (2.0f * (float)f) / 128.0f;
    float inv = 1.0f / powf(10000.0f, e);
    float ang = (float)s * inv;
    cosT[id] = cosf(ang);
    sinT[id] = sinf(ang);
}

// ---------------------------------------------------------------------------
// fp32 -> bf16 conversion, float4-vectorized grid-stride.
// ---------------------------------------------------------------------------
__global__ void conv_bf16(const float* __restrict__ in, bfu* __restrict__ out, int n4) {
    for (int i = blockIdx.x * 256 + threadIdx.x; i < n4; i += gridDim.x * 256) {
        float4 v = ((const float4*)in)[i];
        ushort4 o;
        o.x = f2bf(v.x); o.y = f2bf(v.y); o.z = f2bf(v.z); o.w = f2bf(v.w);
        ((ushort4*)out)[i] = o;
    }
}

// ---------------------------------------------------------------------------
// Deep-pipelined bf16 MFMA GEMM: BM=256, BN=128, BK=64, 8 waves (2Mx4N),
// 3 LDS buffers (144 KB), counted vmcnt(6) once per K-tile (never 0 in loop),
// T2 XOR-swizzle on fragment reads (pre-swizzled global source), T5 setprio.
// A[M][2048], B[N][2048] K-major bf16. Grid (N/128, M/256), 512 thr.
// EPI=0: fused RoPE+elu+1; writes qb,kb (seq-major) + kT,vT (feature-major).
// EPI=1: fp32 C store.
// ---------------------------------------------------------------------------
template<int EPI>
__global__ __launch_bounds__(512) void gemm8p(
    const bfu* __restrict__ A, const bfu* __restrict__ B,
    const float* __restrict__ cosT, const float* __restrict__ sinT,
    bfu* __restrict__ qb, bfu* __restrict__ kb,
    bfu* __restrict__ kT, bfu* __restrict__ vT,
    float* __restrict__ outF)
{
    __shared__ bfu AsL[3 * 256 * 64];   // 98304 B
    __shared__ bfu BsL[3 * 128 * 64];   // 49152 B
    const int tid = threadIdx.x;
    const int wid = tid >> 6, lane = tid & 63;
    const int wm = wid >> 2, wn = wid & 3;
    const int bm = blockIdx.y * 256, bn = blockIdx.x * 128;
    const int l15 = lane & 15, l7 = lane & 7, lhi = lane >> 4;

    // fragment read byte-offsets (row-major 64-elem rows = 128 B; slot ^= row&7;
    // row&7 == lane&7 since all row bases are multiples of 8)
    const int arow = (wm * 128 + l15) * 128;
    const int brow = (wn * 32 + l15) * 128;
    const int sl0 = ((lhi + 0) ^ l7) * 16;
    const int sl1 = ((lhi + 4) ^ l7) * 16;

    // staging: per instr 512 thr x 16 B = 64 rows; LDS dest linear,
    // global source column pre-swizzled with the same involution.
    const int rl = tid >> 3;                       // 0..63
    const int scol = ((tid & 7) ^ (rl & 7)) * 8;   // elems
    const bfu* Ab = A + (size_t)(bm + rl) * 2048 + scol;
    const bfu* Bb = B + (size_t)(bn + rl) * 2048 + scol;
    bfu* AsW = AsL + wid * 512;                    // wave-uniform dest base
    bfu* BsW = BsL + wid * 512;

    f32x4 acc[8][2] = {};

    // stage half `h` (0/1) of K-tile T into buffer sbuf: 3 gload_lds
    auto stage = [&](int T, int sbuf, int h) {
        const size_t kofs = (size_t)T * 64;
        if (h == 0) {
            g2l16(AsW + sbuf * 16384 + 0 * 4096, Ab + kofs);
            g2l16(AsW + sbuf * 16384 + 1 * 4096, Ab + kofs + 131072);
            g2l16(BsW + sbuf * 8192  + 0 * 4096, Bb + kofs);
        } else {
            g2l16(AsW + sbuf * 16384 + 2 * 4096, Ab + kofs + 262144);
            g2l16(AsW + sbuf * 16384 + 3 * 4096, Ab + kofs + 393216);
            g2l16(BsW + sbuf * 8192  + 1 * 4096, Bb + kofs + 131072);
        }
    };

    // prologue: tiles 0 and 1 fully staged; certify tile 0
    stage(0, 0, 0); stage(0, 0, 1);
    stage(1, 1, 0); stage(1, 1, 1);
    asm volatile("s_waitcnt vmcnt(6)" ::: "memory");
    __builtin_amdgcn_s_barrier();
    asm volatile("" ::: "memory");

    for (int T = 0; T < 32; ++T) {
        const int buf = T % 3;
        const int sbuf = (T + 2) % 3;
        const bool doStage = (T < 30);
        const char* Abl = (const char*)AsL + buf * 32768;
        const char* Bbl = (const char*)BsL + buf * 16384;

        // ---------------- phase 0: mi 0-3 ----------------
        bf16x8 af0[4][2], bfrg[2][2];
#pragma unroll
        for (int mi = 0; mi < 4; ++mi) {
            af0[mi][0] = *(const bf16x8*)(Abl + arow + mi * 2048 + sl0);
            af0[mi][1] = *(const bf16x8*)(Abl + arow + mi * 2048 + sl1);
        }
#pragma unroll
        for (int ni = 0; ni < 2; ++ni) {
            bfrg[ni][0] = *(const bf16x8*)(Bbl + brow + ni * 2048 + sl0);
            bfrg[ni][1] = *(const bf16x8*)(Bbl + brow + ni * 2048 + sl1);
        }
        if (doStage) stage(T + 2, sbuf, 0);
        __builtin_amdgcn_s_barrier();
        asm volatile("s_waitcnt lgkmcnt(0)" ::: "memory");
        __builtin_amdgcn_sched_barrier(0);
        __builtin_amdgcn_s_setprio(1);
#pragma unroll
        for (int mi = 0; mi < 4; ++mi)
#pragma unroll
            for (int ni = 0; ni < 2; ++ni) {
                acc[mi][ni] = __builtin_amdgcn_mfma_f32_16x16x32_bf16(af0[mi][0], bfrg[ni][0], acc[mi][ni], 0, 0, 0);
                acc[mi][ni] = __builtin_amdgcn_mfma_f32_16x16x32_bf16(af0[mi][1], bfrg[ni][1], acc[mi][ni], 0, 0, 0);
            }
        __builtin_amdgcn_s_setprio(0);
        __builtin_amdgcn_s_barrier();
        asm volatile("" ::: "memory");

        // ---------------- phase 1: mi 4-7 (reuse B frags) ----------------
        bf16x8 af1[4][2];
#pragma unroll
        for (int mi = 0; mi < 4; ++mi) {
            af1[mi][0] = *(const bf16x8*)(Abl + arow + (mi + 4) * 2048 + sl0);
            af1[mi][1] = *(const bf16x8*)(Abl + arow + (mi + 4) * 2048 + sl1);
        }
        if (doStage) stage(T + 2, sbuf, 1);
        __builtin_amdgcn_s_barrier();
        asm volatile("s_waitcnt lgkmcnt(0)" ::: "memory");
        __builtin_amdgcn_sched_barrier(0);
        __builtin_amdgcn_s_setprio(1);
#pragma unroll
        for (int mi = 0; mi < 4; ++mi)
#pragma unroll
            for (int ni = 0; ni < 2; ++ni) {
                acc[mi + 4][ni] = __builtin_amdgcn_mfma_f32_16x16x32_bf16(af1[mi][0], bfrg[ni][0], acc[mi + 4][ni], 0, 0, 0);
                acc[mi + 4][ni] = __builtin_amdgcn_mfma_f32_16x16x32_bf16(af1[mi][1], bfrg[ni][1], acc[mi + 4][ni], 0, 0, 0);
            }
        __builtin_amdgcn_s_setprio(0);
        // end of K-tile: certify next tile's staging (counted, never 0 mid-loop)
        if (T < 30) { asm volatile("s_waitcnt vmcnt(6)" ::: "memory"); }
        else        { asm volatile("s_waitcnt vmcnt(0)" ::: "memory"); }
        __builtin_amdgcn_s_barrier();
        asm volatile("" ::: "memory");
    }

    // ---------------- epilogue ----------------
    if constexpr (EPI == 0) {
        const int part = bn >> 11;             // 0=q 1=k 2=v (uniform)
        const int headcol = bn & 2047;         // head*128 (uniform)
        const int head = headcol >> 7;
#pragma unroll
        for (int mi = 0; mi < 8; ++mi) {
            const int m0 = bm + wm * 128 + mi * 16 + (lhi << 2);
            const int bq = m0 >> 12;
            const int sloc = m0 & 4095;
#pragma unroll
            for (int ni = 0; ni < 2; ++ni) {
                const int d = wn * 32 + ni * 16 + l15;
                const int f = d & 63;
                float vv[4];
#pragma unroll
                for (int r = 0; r < 4; ++r) {
                    float v = acc[mi][ni][r];
                    float p = __shfl_xor(v, 1);      // partner d^1 (lane^1)
                    if (part < 2) {
                        const int s = (m0 + r) & 4095;
                        float cc = cosT[s * 64 + f], sn = sinT[s * 64 + f];
                        float o = (d & 1) ? v * cc + p * sn : v * cc - p * sn;
                        v = o > 0.0f ? o + 1.0f : __expf(o);
                    }
                    vv[r] = v;
                }
                if (part == 0) {
#pragma unroll
                    for (int r = 0; r < 4; ++r)
                        qb[(size_t)(m0 + r) * 2048 + headcol + d] = f2bf(vv[r]);
                } else if (part == 1) {
#pragma unroll
                    for (int r = 0; r < 4; ++r)
                        kb[(size_t)(m0 + r) * 2048 + headcol + d] = f2bf(vv[r]);
                    ushort4 t4;
                    t4.x = f2bf(vv[0]); t4.y = f2bf(vv[1]); t4.z = f2bf(vv[2]); t4.w = f2bf(vv[3]);
                    *(ushort4*)(kT + ((size_t)(bq * 16 + head) * 128 + d) * 4096 + sloc) = t4;
                } else {
                    ushort4 t4;
                    t4.x = f2bf(vv[0]); t4.y = f2bf(vv[1]); t4.z = f2bf(vv[2]); t4.w = f2bf(vv[3]);
                    *(ushort4*)(vT + ((size_t)(bq * 16 + head) * 128 + d) * 4096 + sloc) = t4;
                }
            }
        }
    } else {
#pragma unroll
        for (int mi = 0; mi < 8; ++mi) {
            const int m0 = bm + wm * 128 + mi * 16 + (lhi << 2);
#pragma unroll
            for (int ni = 0; ni < 2; ++ni) {
                const int n = bn + wn * 32 + ni * 16 + l15;
#pragma unroll
                for (int r = 0; r < 4; ++r)
                    outF[(size_t)(m0 + r) * 2048 + n] = acc[mi][ni][r];
            }
        }
    }
}

// ---------------------------------------------------------------------------
// Per (b,h,c): S^T[e][d] = P(vT, kT) over chunk (K=256), + Zc[d] = sum_l k[l][d].
// Output Scb bf16 [batch][e][d]. Grid 512, 256 thr.
// ---------------------------------------------------------------------------
__global__ __launch_bounds__(256) void kv_outer_mfma(
    const bfu* __restrict__ vT, const bfu* __restrict__ kT,
    bfu* __restrict__ Scb, float* __restrict__ Zc)
{
    __shared__ bfu As[128 * 64];   // vT tile (e rows)
    __shared__ bfu Bs[128 * 64];   // kT tile (d rows)
    __shared__ float zS[128][2];
    const int batch = blockIdx.x;
    const int c = batch & 15, h = (batch >> 4) & 15, b = batch >> 8;
    const size_t fbase = (size_t)(b * 16 + h) * 128 * 4096 + c * 256;
    const int tid = threadIdx.x, wid = tid >> 6, lane = tid & 63;
    const int wr = wid >> 1, wc = wid & 1;
    const int srow = lane >> 3, scol = (lane & 7) * 8;
    f32x4 acc[4][4] = {};
    float zreg = 0.0f;
    const int zd = tid >> 1, zo = (tid & 1) * 32;

    for (int k0 = 0; k0 < 256; k0 += 64) {
        __syncthreads();
#pragma unroll
        for (int i = 0; i < 4; ++i) {
            const int r = i * 32 + wid * 8;
            g2l16(&As[r * 64], vT + fbase + (size_t)(r + srow) * 4096 + k0 + scol);
            g2l16(&Bs[r * 64], kT + fbase + (size_t)(r + srow) * 4096 + k0 + scol);
        }
        __syncthreads();
#pragma unroll
        for (int ks = 0; ks < 2; ++ks) {
            bf16x8 af[4], bfr[4];
#pragma unroll
            for (int mi = 0; mi < 4; ++mi)
                af[mi] = *(const bf16x8*)&As[(wr * 64 + mi * 16 + (lane & 15)) * 64 + ks * 32 + (lane >> 4) * 8];
#pragma unroll
            for (int ni = 0; ni < 4; ++ni)
                bfr[ni] = *(const bf16x8*)&Bs[(wc * 64 + ni * 16 + (lane & 15)) * 64 + ks * 32 + (lane >> 4) * 8];
#pragma unroll
            for (int mi = 0; mi < 4; ++mi)
#pragma unroll
                for (int ni = 0; ni < 4; ++ni)
                    acc[mi][ni] = __builtin_amdgcn_mfma_f32_16x16x32_bf16(af[mi], bfr[ni], acc[mi][ni], 0, 0, 0);
        }
        // Z partial sums from kT tile (rows = d)
#pragma unroll
        for (int j = 0; j < 32; ++j) zreg += bf2f(Bs[zd * 64 + zo + j]);
    }
    zS[zd][tid & 1] = zreg;
    __syncthreads();
    if (tid < 128) Zc[(size_t)batch * 128 + tid] = zS[tid][0] + zS[tid][1];
    bfu* Sout = Scb + (size_t)batch * 16384;
#pragma unroll
    for (int mi = 0; mi < 4; ++mi)
#pragma unroll
        for (int ni = 0; ni < 4; ++ni) {
            const int d = wc * 64 + ni * 16 + (lane & 15);
#pragma unroll
            for (int r = 0; r < 4; ++r) {
                const int e = wr * 64 + mi * 16 + ((lane >> 4) << 2) + r;
                Sout[e * 128 + d] = f2bf(acc[mi][ni][r]);
            }
        }
}

// ---------------------------------------------------------------------------
// Exclusive prefixes over chunks (in place). Scb bf16 (fp32 running sum).
// ---------------------------------------------------------------------------
__global__ void prefix_Sb(bfu* __restrict__ Scb) {
    size_t idx = (size_t)blockIdx.x * 256 + threadIdx.x;  // 32*16384
    size_t bh = idx >> 14, de = idx & 16383;
    bfu* p = Scb + bh * (size_t)NCh * 16384 + de;
    float run = 0.0f;
#pragma unroll
    for (int c = 0; c < NCh; ++c) {
        float t = bf2f(p[(size_t)c * 16384]);
        p[(size_t)c * 16384] = f2bf(run);
        run += t;
    }
}
__global__ void prefix_Z(float* __restrict__ Zc) {
    size_t idx = (size_t)blockIdx.x * 256 + threadIdx.x;  // 32*128
    size_t bh = idx >> 7, d = idx & 127;
    float* p = Zc + bh * (size_t)NCh * 128 + d;
    float run = 0.0f;
#pragma unroll
    for (int c = 0; c < NCh; ++c) {
        float t = p[(size_t)c * 128];
        p[(size_t)c * 128] = run;
        run += t;
    }
}

// ---------------------------------------------------------------------------
// MFMA chunk attention. Grid (2 halves, 512 batch), 256 thr / 4 waves (2x2).
// ---------------------------------------------------------------------------
__global__ __launch_bounds__(256) void chunk_mfma(
    const bfu* __restrict__ qb, const bfu* __restrict__ kb,
    const bfu* __restrict__ vT, const bfu* __restrict__ Scb,
    const float* __restrict__ Zc, bfu* __restrict__ ao)
{
    __shared__ bfu shrd[16384];    // k tile [m][128] / vT tile [e][128] / S^T tile
    __shared__ bfu attL[16384];    // att [l][m] bf16, byte ^ ((l&7)<<4)
    __shared__ float Zs[128];
    __shared__ float denS[128][2];
    const int half = blockIdx.x, batch = blockIdx.y;
    const int c = batch & 15, h = (batch >> 4) & 15, b = batch >> 8;
    const int row0 = b * Ss + c * CK;
    const int tid = threadIdx.x, wid = tid >> 6, lane = tid & 63;
    const int wr = wid >> 1, wc = wid & 1;
    const int sr = lane >> 4, sc8 = (lane & 15) * 8;
    if (tid < 128) Zs[tid] = Zc[(size_t)batch * 128 + tid];

    bf16x8 qf[4][4];
    {
        const bfu* qrow = qb + (size_t)(row0 + half * 128 + wr * 64 + (lane & 15)) * 2048
                          + h * 128 + (lane >> 4) * 8;
#pragma unroll
        for (int mi = 0; mi < 4; ++mi)
#pragma unroll
            for (int ks = 0; ks < 4; ++ks)
                qf[mi][ks] = *(const bf16x8*)(qrow + (size_t)mi * 16 * 2048 + ks * 32);
    }
    f32x4 num[4][4] = {};
    float den_reg = 0.0f;
    const int dl = tid >> 1, dc0 = (tid & 1) * 64;

    for (int kb_ = 0; kb_ <= half; ++kb_) {
        __syncthreads();
#pragma unroll
        for (int i = 0; i < 8; ++i) {
            const int r = i * 16 + wid * 4;
            g2l16(&shrd[r * 128], kb + (size_t)(row0 + kb_ * 128 + r + sr) * 2048 + h * 128 + sc8);
        }
        __syncthreads();
        f32x4 attacc[4][4] = {};
#pragma unroll
        for (int ks = 0; ks < 4; ++ks) {
            bf16x8 bfr[4];
#pragma unroll
            for (int ni = 0; ni < 4; ++ni)
                bfr[ni] = *(const bf16x8*)&shrd[(wc * 64 + ni * 16 + (lane & 15)) * 128 + ks * 32 + (lane >> 4) * 8];
#pragma unroll
            for (int mi = 0; mi < 4; ++mi)
#pragma unroll
                for (int ni = 0; ni < 4; ++ni)
                    attacc[mi][ni] = __builtin_amdgcn_mfma_f32_16x16x32_bf16(qf[mi][ks], bfr[ni], attacc[mi][ni], 0, 0, 0);
        }
        __syncthreads();
#pragma unroll
        for (int i = 0; i < 8; ++i) {
            const int r = i * 16 + wid * 4;
            g2l16(&shrd[r * 128],
                  vT + ((size_t)(b * 16 + h) * 128 + r + sr) * 4096 + c * 256 + kb_ * 128 + sc8);
        }
        const bool needmask = (kb_ == half);
#pragma unroll
        for (int mi = 0; mi < 4; ++mi)
#pragma unroll
            for (int ni = 0; ni < 4; ++ni) {
                const int l0 = wr * 64 + mi * 16 + ((lane >> 4) << 2);
                const int m = wc * 64 + ni * 16 + (lane & 15);
#pragma unroll
                for (int r = 0; r < 4; ++r) {
                    const int l = l0 + r;
                    float v = attacc[mi][ni][r];
                    if (needmask && (half * 128 + l) < (kb_ * 128 + m)) v = 0.0f;
                    const int byte = (l * 256 + m * 2) ^ ((l & 7) << 4);
                    *(bfu*)((char*)attL + byte) = f2bf(v);
                }
            }
        __syncthreads();
#pragma unroll
        for (int ks = 0; ks < 4; ++ks) {
            bf16x8 af[4], bfr[4];
#pragma unroll
            for (int mi = 0; mi < 4; ++mi) {
                const int l = wr * 64 + mi * 16 + (lane & 15);
                const int byte = (l * 256 + (ks * 32 + (lane >> 4) * 8) * 2) ^ ((l & 7) << 4);
                af[mi] = *(const bf16x8*)((const char*)attL + byte);
            }
#pragma unroll
            for (int ni = 0; ni < 4; ++ni)
                bfr[ni] = *(const bf16x8*)&shrd[(wc * 64 + ni * 16 + (lane & 15)) * 128 + ks * 32 + (lane >> 4) * 8];
#pragma unroll
            for (int mi = 0; mi < 4; ++mi)
#pragma unroll
                for (int ni = 0; ni < 4; ++ni)
                    num[mi][ni] = __builtin_amdgcn_mfma_f32_16x16x32_bf16(af[mi], bfr[ni], num[mi][ni], 0, 0, 0);
        }
#pragma unroll
        for (int j8 = 0; j8 < 8; ++j8) {
            const int byte = (dl * 256 + (dc0 + j8 * 8) * 2) ^ ((dl & 7) << 4);
            u16x8 a = *(const u16x8*)((const char*)attL + byte);
#pragma unroll
            for (int jj = 0; jj < 8; ++jj) den_reg += bf2f(a[jj]);
        }
    }
    __syncthreads();
#pragma unroll
    for (int i = 0; i < 8; ++i) {
        const int r = i * 16 + wid * 4;
        g2l16(&shrd[r * 128], Scb + (size_t)batch * 16384 + (size_t)(r + sr) * 128 + sc8);
    }
    __syncthreads();
#pragma unroll
    for (int ks = 0; ks < 4; ++ks) {
        bf16x8 bfr[4];
#pragma unroll
        for (int ni = 0; ni < 4; ++ni)
            bfr[ni] = *(const bf16x8*)&shrd[(wc * 64 + ni * 16 + (lane & 15)) * 128 + ks * 32 + (lane >> 4) * 8];
#pragma unroll
        for (int mi = 0; mi < 4; ++mi)
#pragma unroll
            for (int ni = 0; ni < 4; ++ni)
                num[mi][ni] = __builtin_amdgcn_mfma_f32_16x16x32_bf16(qf[mi][ks], bfr[ni], num[mi][ni], 0, 0, 0);
    }
    {
        const bfu* qrow = qb + (size_t)(row0 + half * 128 + dl) * 2048 + h * 128 + dc0;
#pragma unroll
        for (int j8 = 0; j8 < 8; ++j8) {
            u16x8 a = *(const u16x8*)(qrow + j8 * 8);
#pragma unroll
            for (int jj = 0; jj < 8; ++jj) den_reg += bf2f(a[jj]) * Zs[dc0 + j8 * 8 + jj];
        }
    }
    denS[dl][tid & 1] = den_reg;
    __syncthreads();
    bfu* aop = ao + (size_t)(row0 + half * 128) * 2048 + h * 128;
#pragma unroll
    for (int mi = 0; mi < 4; ++mi)
#pragma unroll
        for (int ni = 0; ni < 4; ++ni) {
            const int e = wc * 64 + ni * 16 + (lane & 15);
#pragma unroll
            for (int r = 0; r < 4; ++r) {
                const int l = wr * 64 + mi * 16 + ((lane >> 4) << 2) + r;
                float dv = denS[l][0] + denS[l][1];
                dv = dv > 1e-6f ? dv : 1e-6f;
                aop[(size_t)l * 2048 + e] = f2bf(num[mi][ni][r] / dv);
            }
        }
}

// ---------------------------------------------------------------------------
extern "C" void kernel_launch(void* const* d_in, const int* in_sizes, int n_in,
                              void* d_out, int out_size, void* d_ws, size_t ws_size,
                              hipStream_t stream)
{
    const float* x    = (const float*)d_in[0];
    const float* Wqkv = (const float*)d_in[1];
    const float* Wout = (const float*)d_in[2];
    float* out = (float*)d_out;
    char* ws = (char*)d_ws;

    // byte layout (~202.3 MB total, proven safe in rounds 2-4):
    bfu* xb   = (bfu*)(ws);                    // 16,777,216 elems; ao aliases after qkv gemm
    bfu* ao   = (bfu*)(ws);
    bfu* wqb  = (bfu*)(ws + 33554432);         // 12,582,912 elems; wob aliases after
    bfu* wob  = (bfu*)(ws + 33554432);         //  4,194,304 elems
    float* cosT = (float*)(ws + 58720256);     // 262,144
    float* sinT = (float*)(ws + 59768832);     // 262,144
    bfu* Scb  = (bfu*)(ws + 60817408);         // 8,388,608 elems (bf16 S^T states)
    float* Zc = (float*)(ws + 77594624);       // 65,536
    bfu* qb   = (bfu*)(ws + 77856768);         // 16,777,216
    bfu* kb   = (bfu*)(ws + 111411200);        // 16,777,216
    bfu* kTb  = (bfu*)(ws + 144965632);        // 16,777,216
    bfu* vTb  = (bfu*)(ws + 178520064);        // 16,777,216  (end 212,074,496)

    rope_table<<<1024, 256, 0, stream>>>(cosT, sinT);
    conv_bf16<<<2048, 256, 0, stream>>>(x,    xb,  4194304);
    conv_bf16<<<2048, 256, 0, stream>>>(Wqkv, wqb, 3145728);
    gemm8p<0><<<dim3(48, 32), 512, 0, stream>>>(xb, wqb, cosT, sinT, qb, kb, kTb, vTb, nullptr);
    conv_bf16<<<1024, 256, 0, stream>>>(Wout, wob, 1048576);   // xb dead now
    kv_outer_mfma<<<512, 256, 0, stream>>>(vTb, kTb, Scb, Zc);
    prefix_Z<<<16, 256, 0, stream>>>(Zc);
    prefix_Sb<<<2048, 256, 0, stream>>>(Scb);
    chunk_mfma<<<dim3(2, 512), 256, 0, stream>>>(qb, kb, vTb, Scb, Zc, ao);
    gemm8p<1><<<dim3(16, 32), 512, 0, stream>>>(ao, wob, nullptr, nullptr, nullptr, nullptr, nullptr, nullptr, out);
}

// Round 6
// 471.349 us; speedup vs baseline: 7.8833x; 1.0885x over previous
//
#include <hip/hip_runtime.h>
#include <cmath>

#define Ss 4096
#define NCh 16
#define CK 256

typedef unsigned short bfu;
typedef __bf16 bf16x8 __attribute__((ext_vector_type(8)));
typedef float f32x4 __attribute__((ext_vector_type(4)));
typedef unsigned short u16x8 __attribute__((ext_vector_type(8)));

__device__ __forceinline__ float bf2f(unsigned short u) {
    union { unsigned u32; float f; } v; v.u32 = ((unsigned)u) << 16; return v.f;
}
__device__ __forceinline__ unsigned short f2bf(float f) {
    union { float f; unsigned u; } v; v.f = f;
    unsigned r = v.u + 0x7fff + ((v.u >> 16) & 1);
    return (unsigned short)(r >> 16);
}

// async global->LDS, 16B per lane. lds base wave-uniform; g per-lane.
__device__ __forceinline__ void g2l16(void* lds, const void* g) {
    __builtin_amdgcn_global_load_lds(
        (const __attribute__((address_space(1))) void*)g,
        (__attribute__((address_space(3))) void*)lds, 16, 0, 0);
}

#define MFMA __builtin_amdgcn_mfma_f32_16x16x32_bf16

// ---------------------------------------------------------------------------
// RoPE tables, compact [s][f], f = d & 63 (4096 x 64 each).
// ---------------------------------------------------------------------------
__global__ void rope_table(float* __restrict__ cosT, float* __restrict__ sinT) {
    int id = blockIdx.x * 256 + threadIdx.x;      // 262144
    int f = id & 63, s = id >> 6;
    float e = (2.0f * (float)f) / 128.0f;
    float inv = 1.0f / powf(10000.0f, e);
    float ang = (float)s * inv;
    cosT[id] = cosf(ang);
    sinT[id] = sinf(ang);
}

// ---------------------------------------------------------------------------
// fp32 -> bf16 conversion, float4-vectorized grid-stride.
// ---------------------------------------------------------------------------
__global__ void conv_bf16(const float* __restrict__ in, bfu* __restrict__ out, int n4) {
    for (int i = blockIdx.x * 256 + threadIdx.x; i < n4; i += gridDim.x * 256) {
        float4 v = ((const float4*)in)[i];
        ushort4 o;
        o.x = f2bf(v.x); o.y = f2bf(v.y); o.z = f2bf(v.z); o.w = f2bf(v.w);
        ((ushort4*)out)[i] = o;
    }
}

// ---------------------------------------------------------------------------
// 256x256 bf16 MFMA GEMM, BK=64, 8 waves (2M x 4N), per-wave 128x64 output.
// 2-slot double-buffered LDS (128 KB). Region-death pipeline:
//   ph0: read A(mi0-3)+B(ni0-1), MFMA q00
//   ph1: read B(ni2-3), MFMA q01, BARRIER (B[T] dead)
//   ph2: read A(mi4-7), stage B(T+2) -> same slot, MFMA q10, BARRIER (A[T] dead)
//   ph3: stage A(T+2), MFMA q11, vmcnt(8) (certify T+1), BARRIER
// Counted vmcnt: T+1's loads were issued during T-1 -> ~5 phases of cover.
// XCD-aware bijective block swizzle (nwg % 8 == 0).
// A[M][2048], B[N][2048] K-major bf16. Grid 1-D (nbx*nby), 512 thr.
// EPI=0: fused RoPE+elu+1 -> qb,kb,kT,vT.  EPI=1: fp32 C store.
// ---------------------------------------------------------------------------
template<int EPI>
__global__ __launch_bounds__(512) void gemm256(
    const bfu* __restrict__ A, const bfu* __restrict__ B, int nbx,
    const float* __restrict__ cosT, const float* __restrict__ sinT,
    bfu* __restrict__ qb, bfu* __restrict__ kb,
    bfu* __restrict__ kT, bfu* __restrict__ vT,
    float* __restrict__ outF)
{
    __shared__ bfu AsL[2 * 256 * 64];   // 65536 B
    __shared__ bfu BsL[2 * 256 * 64];   // 65536 B
    const int nwg = gridDim.x;
    const int q8 = nwg >> 3;
    const int swz = (blockIdx.x & 7) * q8 + (blockIdx.x >> 3);
    const int bm = (swz / nbx) * 256, bn = (swz % nbx) * 256;

    const int tid = threadIdx.x;
    const int wid = tid >> 6, lane = tid & 63;
    const int wm = wid >> 2, wn = wid & 3;
    const int l15 = lane & 15, l7 = lane & 7, lhi = lane >> 4;

    // staging: 512 thr x 16 B = 64 rows x 128 B per instruction.
    // LDS dest linear; global source column pre-swizzled (involution = read XOR).
    const int rl = tid >> 3;
    const int scol = ((tid & 7) ^ (rl & 7)) * 8;
    const bfu* Ab = A + (size_t)(bm + rl) * 2048 + scol;
    const bfu* Bb = B + (size_t)(bn + rl) * 2048 + scol;

    f32x4 acc[8][4] = {};

    auto stageA = [&](int T) {
        bfu* d = AsL + (T & 1) * 16384 + wid * 512;
        const bfu* s = Ab + (size_t)T * 64;
        g2l16(d,         s);
        g2l16(d + 4096,  s + (size_t)64 * 2048);
        g2l16(d + 8192,  s + (size_t)128 * 2048);
        g2l16(d + 12288, s + (size_t)192 * 2048);
    };
    auto stageB = [&](int T) {
        bfu* d = BsL + (T & 1) * 16384 + wid * 512;
        const bfu* s = Bb + (size_t)T * 64;
        g2l16(d,         s);
        g2l16(d + 4096,  s + (size_t)64 * 2048);
        g2l16(d + 8192,  s + (size_t)128 * 2048);
        g2l16(d + 12288, s + (size_t)192 * 2048);
    };

    // prologue: tiles 0,1 staged; certify tile 0 (vmcnt(8) leaves tile 1 in flight)
    stageA(0); stageB(0);
    stageA(1); stageB(1);
    asm volatile("s_waitcnt vmcnt(8)" ::: "memory");
    __builtin_amdgcn_s_barrier();
    asm volatile("" ::: "memory");

    for (int T = 0; T < 32; ++T) {
        const char* Ax = (const char*)AsL + (T & 1) * 32768;
        const char* Bx = (const char*)BsL + (T & 1) * 32768;
        bf16x8 a0[4][2], a1[4][2], b0[2][2], b1[2][2];

        // ---- ph0: A(mi0-3) + B(ni0-1) reads; MFMA q00 ----
#pragma unroll
        for (int mi = 0; mi < 4; ++mi)
#pragma unroll
            for (int ks = 0; ks < 2; ++ks)
                a0[mi][ks] = *(const bf16x8*)(Ax + (wm * 128 + mi * 16 + l15) * 128 + (((ks * 4 + lhi) ^ l7) << 4));
#pragma unroll
        for (int ni = 0; ni < 2; ++ni)
#pragma unroll
            for (int ks = 0; ks < 2; ++ks)
                b0[ni][ks] = *(const bf16x8*)(Bx + (wn * 64 + ni * 16 + l15) * 128 + (((ks * 4 + lhi) ^ l7) << 4));
        asm volatile("s_waitcnt lgkmcnt(0)" ::: "memory");
        __builtin_amdgcn_sched_barrier(0);
        __builtin_amdgcn_s_setprio(1);
#pragma unroll
        for (int mi = 0; mi < 4; ++mi)
#pragma unroll
            for (int ni = 0; ni < 2; ++ni) {
                acc[mi][ni] = MFMA(a0[mi][0], b0[ni][0], acc[mi][ni], 0, 0, 0);
                acc[mi][ni] = MFMA(a0[mi][1], b0[ni][1], acc[mi][ni], 0, 0, 0);
            }
        __builtin_amdgcn_s_setprio(0);

        // ---- ph1: B(ni2-3) reads; MFMA q01; barrier = B[T] dead ----
#pragma unroll
        for (int ni = 0; ni < 2; ++ni)
#pragma unroll
            for (int ks = 0; ks < 2; ++ks)
                b1[ni][ks] = *(const bf16x8*)(Bx + (wn * 64 + (ni + 2) * 16 + l15) * 128 + (((ks * 4 + lhi) ^ l7) << 4));
        asm volatile("s_waitcnt lgkmcnt(0)" ::: "memory");
        __builtin_amdgcn_sched_barrier(0);
        __builtin_amdgcn_s_setprio(1);
#pragma unroll
        for (int mi = 0; mi < 4; ++mi)
#pragma unroll
            for (int ni = 0; ni < 2; ++ni) {
                acc[mi][ni + 2] = MFMA(a0[mi][0], b1[ni][0], acc[mi][ni + 2], 0, 0, 0);
                acc[mi][ni + 2] = MFMA(a0[mi][1], b1[ni][1], acc[mi][ni + 2], 0, 0, 0);
            }
        __builtin_amdgcn_s_setprio(0);
        __builtin_amdgcn_s_barrier();
        asm volatile("" ::: "memory");

        // ---- ph2: A(mi4-7) reads; stage B(T+2) (B region free); MFMA q10; barrier = A[T] dead ----
#pragma unroll
        for (int mi = 0; mi < 4; ++mi)
#pragma unroll
            for (int ks = 0; ks < 2; ++ks)
                a1[mi][ks] = *(const bf16x8*)(Ax + (wm * 128 + (mi + 4) * 16 + l15) * 128 + (((ks * 4 + lhi) ^ l7) << 4));
        if (T < 30) stageB(T + 2);
        asm volatile("s_waitcnt lgkmcnt(0)" ::: "memory");
        __builtin_amdgcn_sched_barrier(0);
        __builtin_amdgcn_s_setprio(1);
#pragma unroll
        for (int mi = 0; mi < 4; ++mi)
#pragma unroll
            for (int ni = 0; ni < 2; ++ni) {
                acc[mi + 4][ni] = MFMA(a1[mi][0], b0[ni][0], acc[mi + 4][ni], 0, 0, 0);
                acc[mi + 4][ni] = MFMA(a1[mi][1], b0[ni][1], acc[mi + 4][ni], 0, 0, 0);
            }
        __builtin_amdgcn_s_setprio(0);
        __builtin_amdgcn_s_barrier();
        asm volatile("" ::: "memory");

        // ---- ph3: stage A(T+2) (A region free); MFMA q11; certify T+1; barrier ----
        if (T < 30) stageA(T + 2);
        __builtin_amdgcn_s_setprio(1);
#pragma unroll
        for (int mi = 0; mi < 4; ++mi)
#pragma unroll
            for (int ni = 0; ni < 2; ++ni) {
                acc[mi + 4][ni + 2] = MFMA(a1[mi][0], b1[ni][0], acc[mi + 4][ni + 2], 0, 0, 0);
                acc[mi + 4][ni + 2] = MFMA(a1[mi][1], b1[ni][1], acc[mi + 4][ni + 2], 0, 0, 0);
            }
        __builtin_amdgcn_s_setprio(0);
        if (T < 30) { asm volatile("s_waitcnt vmcnt(8)" ::: "memory"); }
        else        { asm volatile("s_waitcnt vmcnt(0)" ::: "memory"); }
        __builtin_amdgcn_s_barrier();
        asm volatile("" ::: "memory");
    }

    // ---------------- epilogue ----------------
    if constexpr (EPI == 0) {
        const int part = bn >> 11;             // 0=q 1=k 2=v (uniform per block)
#pragma unroll
        for (int mi = 0; mi < 8; ++mi) {
            const int m0 = bm + wm * 128 + mi * 16 + (lhi << 2);
            const int bq = m0 >> 12;
            const int sloc = m0 & 4095;
#pragma unroll
            for (int ni = 0; ni < 4; ++ni) {
                const int cp = (bn & 2047) + wn * 64 + ni * 16 + l15;  // col within part
                const int d = cp & 127;
                const int head = cp >> 7;
                const int f = d & 63;
                float vv[4];
#pragma unroll
                for (int r = 0; r < 4; ++r) {
                    float v = acc[mi][ni][r];
                    float p = __shfl_xor(v, 1);      // partner d^1 (lane^1)
                    if (part < 2) {
                        const int s = (m0 + r) & 4095;
                        float cc = cosT[s * 64 + f], sn = sinT[s * 64 + f];
                        float o = (d & 1) ? v * cc + p * sn : v * cc - p * sn;
                        v = o > 0.0f ? o + 1.0f : __expf(o);
                    }
                    vv[r] = v;
                }
                if (part == 0) {
#pragma unroll
                    for (int r = 0; r < 4; ++r)
                        qb[(size_t)(m0 + r) * 2048 + cp] = f2bf(vv[r]);
                } else if (part == 1) {
#pragma unroll
                    for (int r = 0; r < 4; ++r)
                        kb[(size_t)(m0 + r) * 2048 + cp] = f2bf(vv[r]);
                    ushort4 t4;
                    t4.x = f2bf(vv[0]); t4.y = f2bf(vv[1]); t4.z = f2bf(vv[2]); t4.w = f2bf(vv[3]);
                    *(ushort4*)(kT + ((size_t)(bq * 16 + head) * 128 + d) * 4096 + sloc) = t4;
                } else {
                    ushort4 t4;
                    t4.x = f2bf(vv[0]); t4.y = f2bf(vv[1]); t4.z = f2bf(vv[2]); t4.w = f2bf(vv[3]);
                    *(ushort4*)(vT + ((size_t)(bq * 16 + head) * 128 + d) * 4096 + sloc) = t4;
                }
            }
        }
    } else {
#pragma unroll
        for (int mi = 0; mi < 8; ++mi) {
            const int m0 = bm + wm * 128 + mi * 16 + (lhi << 2);
#pragma unroll
            for (int ni = 0; ni < 4; ++ni) {
                const int n = bn + wn * 64 + ni * 16 + l15;
#pragma unroll
                for (int r = 0; r < 4; ++r)
                    outF[(size_t)(m0 + r) * 2048 + n] = acc[mi][ni][r];
            }
        }
    }
}

// ---------------------------------------------------------------------------
// Per (b,h,c): S^T[e][d] = P(vT, kT) over chunk (K=256), + Zc[d] = sum_l k[l][d].
// Output Scb bf16 [batch][e][d]. Grid 512, 256 thr.
// ---------------------------------------------------------------------------
__global__ __launch_bounds__(256) void kv_outer_mfma(
    const bfu* __restrict__ vT, const bfu* __restrict__ kT,
    bfu* __restrict__ Scb, float* __restrict__ Zc)
{
    __shared__ bfu As[128 * 64];   // vT tile (e rows)
    __shared__ bfu Bs[128 * 64];   // kT tile (d rows)
    __shared__ float zS[128][2];
    const int batch = blockIdx.x;
    const int c = batch & 15, h = (batch >> 4) & 15, b = batch >> 8;
    const size_t fbase = (size_t)(b * 16 + h) * 128 * 4096 + c * 256;
    const int tid = threadIdx.x, wid = tid >> 6, lane = tid & 63;
    const int wr = wid >> 1, wc = wid & 1;
    const int srow = lane >> 3, scol = (lane & 7) * 8;
    f32x4 acc[4][4] = {};
    float zreg = 0.0f;
    const int zd = tid >> 1, zo = (tid & 1) * 32;

    for (int k0 = 0; k0 < 256; k0 += 64) {
        __syncthreads();
#pragma unroll
        for (int i = 0; i < 4; ++i) {
            const int r = i * 32 + wid * 8;
            g2l16(&As[r * 64], vT + fbase + (size_t)(r + srow) * 4096 + k0 + scol);
            g2l16(&Bs[r * 64], kT + fbase + (size_t)(r + srow) * 4096 + k0 + scol);
        }
        __syncthreads();
#pragma unroll
        for (int ks = 0; ks < 2; ++ks) {
            bf16x8 af[4], bfr[4];
#pragma unroll
            for (int mi = 0; mi < 4; ++mi)
                af[mi] = *(const bf16x8*)&As[(wr * 64 + mi * 16 + (lane & 15)) * 64 + ks * 32 + (lane >> 4) * 8];
#pragma unroll
            for (int ni = 0; ni < 4; ++ni)
                bfr[ni] = *(const bf16x8*)&Bs[(wc * 64 + ni * 16 + (lane & 15)) * 64 + ks * 32 + (lane >> 4) * 8];
#pragma unroll
            for (int mi = 0; mi < 4; ++mi)
#pragma unroll
                for (int ni = 0; ni < 4; ++ni)
                    acc[mi][ni] = MFMA(af[mi], bfr[ni], acc[mi][ni], 0, 0, 0);
        }
        // Z partial sums from kT tile (rows = d)
#pragma unroll
        for (int j = 0; j < 32; ++j) zreg += bf2f(Bs[zd * 64 + zo + j]);
    }
    zS[zd][tid & 1] = zreg;
    __syncthreads();
    if (tid < 128) Zc[(size_t)batch * 128 + tid] = zS[tid][0] + zS[tid][1];
    bfu* Sout = Scb + (size_t)batch * 16384;
#pragma unroll
    for (int mi = 0; mi < 4; ++mi)
#pragma unroll
        for (int ni = 0; ni < 4; ++ni) {
            const int d = wc * 64 + ni * 16 + (lane & 15);
#pragma unroll
            for (int r = 0; r < 4; ++r) {
                const int e = wr * 64 + mi * 16 + ((lane >> 4) << 2) + r;
                Sout[e * 128 + d] = f2bf(acc[mi][ni][r]);
            }
        }
}

// ---------------------------------------------------------------------------
// Exclusive prefixes over chunks (in place). Scb bf16 (fp32 running sum).
// ---------------------------------------------------------------------------
__global__ void prefix_Sb(bfu* __restrict__ Scb) {
    size_t idx = (size_t)blockIdx.x * 256 + threadIdx.x;  // 32*16384
    size_t bh = idx >> 14, de = idx & 16383;
    bfu* p = Scb + bh * (size_t)NCh * 16384 + de;
    float run = 0.0f;
#pragma unroll
    for (int c = 0; c < NCh; ++c) {
        float t = bf2f(p[(size_t)c * 16384]);
        p[(size_t)c * 16384] = f2bf(run);
        run += t;
    }
}
__global__ void prefix_Z(float* __restrict__ Zc) {
    size_t idx = (size_t)blockIdx.x * 256 + threadIdx.x;  // 32*128
    size_t bh = idx >> 7, d = idx & 127;
    float* p = Zc + bh * (size_t)NCh * 128 + d;
    float run = 0.0f;
#pragma unroll
    for (int c = 0; c < NCh; ++c) {
        float t = p[(size_t)c * 128];
        p[(size_t)c * 128] = run;
        run += t;
    }
}

// ---------------------------------------------------------------------------
// MFMA chunk attention. Grid (2 halves, 512 batch), 256 thr / 4 waves (2x2).
// ---------------------------------------------------------------------------
__global__ __launch_bounds__(256) void chunk_mfma(
    const bfu* __restrict__ qb, const bfu* __restrict__ kb,
    const bfu* __restrict__ vT, const bfu* __restrict__ Scb,
    const float* __restrict__ Zc, bfu* __restrict__ ao)
{
    __shared__ bfu shrd[16384];    // k tile [m][128] / vT tile [e][128] / S^T tile
    __shared__ bfu attL[16384];    // att [l][m] bf16, byte ^ ((l&7)<<4)
    __shared__ float Zs[128];
    __shared__ float denS[128][2];
    const int half = blockIdx.x, batch = blockIdx.y;
    const int c = batch & 15, h = (batch >> 4) & 15, b = batch >> 8;
    const int row0 = b * Ss + c * CK;
    const int tid = threadIdx.x, wid = tid >> 6, lane = tid & 63;
    const int wr = wid >> 1, wc = wid & 1;
    const int sr = lane >> 4, sc8 = (lane & 15) * 8;
    if (tid < 128) Zs[tid] = Zc[(size_t)batch * 128 + tid];

    bf16x8 qf[4][4];
    {
        const bfu* qrow = qb + (size_t)(row0 + half * 128 + wr * 64 + (lane & 15)) * 2048
                          + h * 128 + (lane >> 4) * 8;
#pragma unroll
        for (int mi = 0; mi < 4; ++mi)
#pragma unroll
            for (int ks = 0; ks < 4; ++ks)
                qf[mi][ks] = *(const bf16x8*)(qrow + (size_t)mi * 16 * 2048 + ks * 32);
    }
    f32x4 num[4][4] = {};
    float den_reg = 0.0f;
    const int dl = tid >> 1, dc0 = (tid & 1) * 64;

    for (int kb_ = 0; kb_ <= half; ++kb_) {
        __syncthreads();
#pragma unroll
        for (int i = 0; i < 8; ++i) {
            const int r = i * 16 + wid * 4;
            g2l16(&shrd[r * 128], kb + (size_t)(row0 + kb_ * 128 + r + sr) * 2048 + h * 128 + sc8);
        }
        __syncthreads();
        f32x4 attacc[4][4] = {};
#pragma unroll
        for (int ks = 0; ks < 4; ++ks) {
            bf16x8 bfr[4];
#pragma unroll
            for (int ni = 0; ni < 4; ++ni)
                bfr[ni] = *(const bf16x8*)&shrd[(wc * 64 + ni * 16 + (lane & 15)) * 128 + ks * 32 + (lane >> 4) * 8];
#pragma unroll
            for (int mi = 0; mi < 4; ++mi)
#pragma unroll
                for (int ni = 0; ni < 4; ++ni)
                    attacc[mi][ni] = MFMA(qf[mi][ks], bfr[ni], attacc[mi][ni], 0, 0, 0);
        }
        __syncthreads();
#pragma unroll
        for (int i = 0; i < 8; ++i) {
            const int r = i * 16 + wid * 4;
            g2l16(&shrd[r * 128],
                  vT + ((size_t)(b * 16 + h) * 128 + r + sr) * 4096 + c * 256 + kb_ * 128 + sc8);
        }
        const bool needmask = (kb_ == half);
#pragma unroll
        for (int mi = 0; mi < 4; ++mi)
#pragma unroll
            for (int ni = 0; ni < 4; ++ni) {
                const int l0 = wr * 64 + mi * 16 + ((lane >> 4) << 2);
                const int m = wc * 64 + ni * 16 + (lane & 15);
#pragma unroll
                for (int r = 0; r < 4; ++r) {
                    const int l = l0 + r;
                    float v = attacc[mi][ni][r];
                    if (needmask && (half * 128 + l) < (kb_ * 128 + m)) v = 0.0f;
                    const int byte = (l * 256 + m * 2) ^ ((l & 7) << 4);
                    *(bfu*)((char*)attL + byte) = f2bf(v);
                }
            }
        __syncthreads();
#pragma unroll
        for (int ks = 0; ks < 4; ++ks) {
            bf16x8 af[4], bfr[4];
#pragma unroll
            for (int mi = 0; mi < 4; ++mi) {
                const int l = wr * 64 + mi * 16 + (lane & 15);
                const int byte = (l * 256 + (ks * 32 + (lane >> 4) * 8) * 2) ^ ((l & 7) << 4);
                af[mi] = *(const bf16x8*)((const char*)attL + byte);
            }
#pragma unroll
            for (int ni = 0; ni < 4; ++ni)
                bfr[ni] = *(const bf16x8*)&shrd[(wc * 64 + ni * 16 + (lane & 15)) * 128 + ks * 32 + (lane >> 4) * 8];
#pragma unroll
            for (int mi = 0; mi < 4; ++mi)
#pragma unroll
                for (int ni = 0; ni < 4; ++ni)
                    num[mi][ni] = MFMA(af[mi], bfr[ni], num[mi][ni], 0, 0, 0);
        }
#pragma unroll
        for (int j8 = 0; j8 < 8; ++j8) {
            const int byte = (dl * 256 + (dc0 + j8 * 8) * 2) ^ ((dl & 7) << 4);
            u16x8 a = *(const u16x8*)((const char*)attL + byte);
#pragma unroll
            for (int jj = 0; jj < 8; ++jj) den_reg += bf2f(a[jj]);
        }
    }
    __syncthreads();
#pragma unroll
    for (int i = 0; i < 8; ++i) {
        const int r = i * 16 + wid * 4;
        g2l16(&shrd[r * 128], Scb + (size_t)batch * 16384 + (size_t)(r + sr) * 128 + sc8);
    }
    __syncthreads();
#pragma unroll
    for (int ks = 0; ks < 4; ++ks) {
        bf16x8 bfr[4];
#pragma unroll
        for (int ni = 0; ni < 4; ++ni)
            bfr[ni] = *(const bf16x8*)&shrd[(wc * 64 + ni * 16 + (lane & 15)) * 128 + ks * 32 + (lane >> 4) * 8];
#pragma unroll
        for (int mi = 0; mi < 4; ++mi)
#pragma unroll
            for (int ni = 0; ni < 4; ++ni)
                num[mi][ni] = MFMA(qf[mi][ks], bfr[ni], num[mi][ni], 0, 0, 0);
    }
    {
        const bfu* qrow = qb + (size_t)(row0 + half * 128 + dl) * 2048 + h * 128 + dc0;
#pragma unroll
        for (int j8 = 0; j8 < 8; ++j8) {
            u16x8 a = *(const u16x8*)(qrow + j8 * 8);
#pragma unroll
            for (int jj = 0; jj < 8; ++jj) den_reg += bf2f(a[jj]) * Zs[dc0 + j8 * 8 + jj];
        }
    }
    denS[dl][tid & 1] = den_reg;
    __syncthreads();
    bfu* aop = ao + (size_t)(row0 + half * 128) * 2048 + h * 128;
#pragma unroll
    for (int mi = 0; mi < 4; ++mi)
#pragma unroll
        for (int ni = 0; ni < 4; ++ni) {
            const int e = wc * 64 + ni * 16 + (lane & 15);
#pragma unroll
            for (int r = 0; r < 4; ++r) {
                const int l = wr * 64 + mi * 16 + ((lane >> 4) << 2) + r;
                float dv = denS[l][0] + denS[l][1];
                dv = dv > 1e-6f ? dv : 1e-6f;
                aop[(size_t)l * 2048 + e] = f2bf(num[mi][ni][r] / dv);
            }
        }
}

// ---------------------------------------------------------------------------
extern "C" void kernel_launch(void* const* d_in, const int* in_sizes, int n_in,
                              void* d_out, int out_size, void* d_ws, size_t ws_size,
                              hipStream_t stream)
{
    const float* x    = (const float*)d_in[0];
    const float* Wqkv = (const float*)d_in[1];
    const float* Wout = (const float*)d_in[2];
    float* out = (float*)d_out;
    char* ws = (char*)d_ws;

    // byte layout (~202.3 MB total, proven safe in rounds 2-5):
    bfu* xb   = (bfu*)(ws);                    // 16,777,216 elems; ao aliases after qkv gemm
    bfu* ao   = (bfu*)(ws);
    bfu* wqb  = (bfu*)(ws + 33554432);         // 12,582,912 elems; wob aliases after
    bfu* wob  = (bfu*)(ws + 33554432);         //  4,194,304 elems
    float* cosT = (float*)(ws + 58720256);     // 262,144
    float* sinT = (float*)(ws + 59768832);     // 262,144
    bfu* Scb  = (bfu*)(ws + 60817408);         // 8,388,608 elems (bf16 S^T states)
    float* Zc = (float*)(ws + 77594624);       // 65,536
    bfu* qb   = (bfu*)(ws + 77856768);         // 16,777,216
    bfu* kb   = (bfu*)(ws + 111411200);        // 16,777,216
    bfu* kTb  = (bfu*)(ws + 144965632);        // 16,777,216
    bfu* vTb  = (bfu*)(ws + 178520064);        // 16,777,216  (end 212,074,496)

    rope_table<<<1024, 256, 0, stream>>>(cosT, sinT);
    conv_bf16<<<2048, 256, 0, stream>>>(x,    xb,  4194304);
    conv_bf16<<<2048, 256, 0, stream>>>(Wqkv, wqb, 3145728);
    // qkv: M=8192, N=6144 -> grid 24*32=768 (768%8==0, swizzle bijective)
    gemm256<0><<<768, 512, 0, stream>>>(xb, wqb, 24, cosT, sinT, qb, kb, kTb, vTb, nullptr);
    conv_bf16<<<1024, 256, 0, stream>>>(Wout, wob, 1048576);   // xb dead now
    kv_outer_mfma<<<512, 256, 0, stream>>>(vTb, kTb, Scb, Zc);
    prefix_Z<<<16, 256, 0, stream>>>(Zc);
    prefix_Sb<<<2048, 256, 0, stream>>>(Scb);
    chunk_mfma<<<dim3(2, 512), 256, 0, stream>>>(qb, kb, vTb, Scb, Zc, ao);
    // out: M=8192, N=2048 -> grid 8*32=256 (256%8==0)
    gemm256<1><<<256, 512, 0, stream>>>(ao, wob, 8, nullptr, nullptr, nullptr, nullptr, nullptr, nullptr, out);
}